// Round 1
// 1001.663 us; speedup vs baseline: 1.1878x; 1.1878x over previous
//
#include <hip/hip_runtime.h>
#include <math.h>

constexpr int cB = 128;
constexpr int cK = 51;
constexpr int cL = 60;
constexpr int cH = 32;
constexpr int cC = 60;           // L*D
constexpr int cKL = 3060;        // K*L
constexpr int cKL32 = 97920;     // K*L*32
constexpr float kLOG2PI = 1.8378770664093453f;

typedef __attribute__((ext_vector_type(8))) short bfrag8;    // 8 bf16 = 4 VGPRs
typedef __attribute__((ext_vector_type(16))) float accf16;   // MFMA 32x32 accumulator
typedef __attribute__((ext_vector_type(4))) unsigned uint4v; // 16B LDS write

__device__ __forceinline__ float fsig(float x) { return 1.0f / (1.0f + __expf(-x)); }
__device__ __forceinline__ float ftanh(float x) {
  float e = __expf(2.0f * x);
  return 1.0f - 2.0f / (e + 1.0f);
}
__device__ __forceinline__ short f2bf(float f) {   // RNE fp32 -> bf16
  union { float f; unsigned u; } v; v.f = f;
  unsigned r = v.u + 0x7FFFu + ((v.u >> 16) & 1u);
  return (short)(r >> 16);
}
__device__ __forceinline__ unsigned pk2bf(float lo, float hi) {  // 2xf32 -> packed 2xbf16 (RNE)
  unsigned r;
  asm("v_cvt_pk_bf16_f32 %0, %1, %2" : "=v"(r) : "v"(lo), "v"(hi));
  return r;
}

// ---------------- q/k projections: rows = B*K = 6528, 8 rows/block ----------------
__global__ __launch_bounds__(256) void qk_kernel(
    const float* __restrict__ x, const float* __restrict__ Wq, const float* __restrict__ bq,
    const float* __restrict__ Wk, const float* __restrict__ bk,
    float* __restrict__ q, float* __restrict__ kx) {
  __shared__ float xs[8][cC];
  const int row0 = blockIdx.x * 8;
  const int tid = threadIdx.x;
  for (int idx = tid; idx < 8 * cC; idx += 256) {
    int lr = idx / cC, t = idx % cC;
    xs[lr][t] = x[(row0 + lr) * cC + t];
  }
  __syncthreads();
  for (int idx = tid; idx < 8 * 2 * cC; idx += 256) {
    int col = idx % cC;
    int r2 = idx / cC;
    int m = r2 & 1, lr = r2 >> 1;
    const float* W = m ? Wk : Wq;
    float acc = m ? bk[col] : bq[col];
    #pragma unroll 4
    for (int t = 0; t < cC; ++t) acc += xs[lr][t] * W[t * cC + col];
    float* outp = m ? kx : q;
    outp[(row0 + lr) * cC + col] = acc;
  }
}

// ---------------- score = q @ reshape(k) / sqrt(60); softmax over axis=1 ----------------
__global__ __launch_bounds__(256) void attn_kernel(
    const float* __restrict__ q, const float* __restrict__ kx, float* __restrict__ graph) {
  __shared__ float qb[cKL];
  __shared__ float kb[cKL];
  __shared__ float sc[cK * cK];
  __shared__ float cmax[cK], csum[cK];
  const int b = blockIdx.x;
  const int tid = threadIdx.x;
  for (int idx = tid; idx < cKL; idx += 256) {
    qb[idx] = q[b * cKL + idx];
    kb[idx] = kx[b * cKL + idx];
  }
  __syncthreads();
  const float scale = 1.0f / sqrtf(60.0f);
  for (int idx = tid; idx < cK * cK; idx += 256) {
    int i = idx / cK, j = idx % cK;
    float acc = 0.0f;
    #pragma unroll 4
    for (int t = 0; t < cC; ++t) acc += qb[i * cC + t] * kb[t * cK + j];
    sc[idx] = acc * scale;
  }
  __syncthreads();
  if (tid < cK) {
    float m = -1e30f;
    for (int i = 0; i < cK; ++i) m = fmaxf(m, sc[i * cK + tid]);
    float ssum = 0.0f;
    for (int i = 0; i < cK; ++i) ssum += __expf(sc[i * cK + tid] - m);
    cmax[tid] = m; csum[tid] = ssum;
  }
  __syncthreads();
  for (int idx = tid; idx < cK * cK; idx += 256) {
    int j = idx % cK;
    graph[b * cK * cK + idx] = __expf(sc[idx] - cmax[j]) / csum[j];
  }
}

// ---------------- LSTM: one wave (64 lanes) per sequence, 4 sequences/block ----------------
__global__ __launch_bounds__(256) void lstm_kernel(
    const float* __restrict__ x, const float* __restrict__ Wih, const float* __restrict__ Whh,
    const float* __restrict__ bih, const float* __restrict__ bhh, float* __restrict__ hout) {
  const int wave = threadIdx.x >> 6;
  const int lane = threadIdx.x & 63;
  const int seq = blockIdx.x * 4 + wave;   // < 6528
  const int j = lane;
  float w0[32], w1[32];
  #pragma unroll
  for (int k2 = 0; k2 < 32; ++k2) {
    w0[k2] = Whh[j * 32 + k2];
    w1[k2] = Whh[(j + 64) * 32 + k2];
  }
  const float wi0 = Wih[j], wi1 = Wih[j + 64];
  const float bb0 = bih[j] + bhh[j];
  const float bb1 = bih[j + 64] + bhh[j + 64];
  const float xr = (lane < cL) ? x[seq * cL + lane] : 0.0f;
  float h = 0.0f, c = 0.0f;
  float* outp = hout + (size_t)seq * cL * cH;
  for (int t = 0; t < cL; ++t) {
    const float xt = __shfl(xr, t);
    float a0 = bb0 + wi0 * xt;
    float a1 = bb1 + wi1 * xt;
    #pragma unroll
    for (int k2 = 0; k2 < 32; ++k2) {
      const float hk = __shfl(h, k2);
      a0 += w0[k2] * hk;
      a1 += w1[k2] * hk;
    }
    const float sA = fsig(a0);
    const float sB = fsig(a1);
    const float tB = ftanh(a1);
    const float p = sA * tB;
    const float sf = __shfl(sA, (lane & 31) + 32);
    const float so = __shfl(sB, (lane & 31) + 32);
    c = sf * c + p;
    h = so * ftanh(c);
    if (lane < 32) outp[t * cH + lane] = h;
  }
}

// ---------------- agg: per b, agg = G^T (51x51) @ H (51x1920), 128-col tiles ----------------
__global__ __launch_bounds__(256) void agg_kernel(
    const float* __restrict__ hbuf, const float* __restrict__ graph,
    float* __restrict__ aggout) {
  __shared__ float G[cK * cK];
  __shared__ __align__(16) float Ht[cK][128];
  const int b = blockIdx.y;
  const int c0 = blockIdx.x * 128;
  const int tid = threadIdx.x;
  for (int idx = tid; idx < cK * cK; idx += 256) G[idx] = graph[b * cK * cK + idx];
  for (int idx = tid; idx < cK * 128; idx += 256) {
    int k = idx >> 7, c = idx & 127;
    Ht[k][c] = hbuf[((size_t)b * cK + k) * 1920 + c0 + c];
  }
  __syncthreads();
  const int jg = tid >> 5;
  const int cg = tid & 31;
  const int cc = cg * 4;
  float4 acc[7];
  #pragma unroll
  for (int jj = 0; jj < 7; ++jj) acc[jj] = make_float4(0.f, 0.f, 0.f, 0.f);
  for (int k = 0; k < cK; ++k) {
    const float4 hv = *reinterpret_cast<const float4*>(&Ht[k][cc]);
    #pragma unroll
    for (int jj = 0; jj < 7; ++jj) {
      const int j = jg + jj * 8;
      const float g = (j < cK) ? G[k * cK + j] : 0.0f;
      acc[jj].x += g * hv.x; acc[jj].y += g * hv.y;
      acc[jj].z += g * hv.z; acc[jj].w += g * hv.w;
    }
  }
  #pragma unroll
  for (int jj = 0; jj < 7; ++jj) {
    const int j = jg + jj * 8;
    if (j < cK) {
      const size_t o = ((size_t)b * cK + j) * 1920 + c0 + cc;
      aggout[o + 0] = acc[jj].x; aggout[o + 1] = acc[jj].y;
      aggout[o + 2] = acc[jj].z; aggout[o + 3] = acc[jj].w;
    }
  }
}

// ---------------- gnn2: per-row h_gcn_pre = relu(agg@Wn + bn + hm@Wr) @ W2 + b2 ----------------
__global__ __launch_bounds__(256) void gnn2_kernel(
    const float* __restrict__ hbuf, const float* __restrict__ Wn,
    const float* __restrict__ bn_, const float* __restrict__ Wr,
    const float* __restrict__ W2, const float* __restrict__ b2,
    float* __restrict__ hg) {
  __shared__ __align__(16) float wn[cH * cH];
  __shared__ __align__(16) float wr[cH * cH];
  __shared__ __align__(16) float w2[cH * cH];
  __shared__ float bnb[cH], b2b[cH];
  __shared__ float A_[192][33];
  __shared__ float M_[192][33];
  const int tid = threadIdx.x;
  const int row0 = blockIdx.x * 192;
  for (int idx = tid; idx < cH * cH; idx += 256) { wn[idx] = Wn[idx]; wr[idx] = Wr[idx]; w2[idx] = W2[idx]; }
  if (tid < cH) { bnb[tid] = bn_[tid]; b2b[tid] = b2[tid]; }
  for (int idx = tid; idx < 192 * 32; idx += 256) {
    const int r = idx >> 5, d = idx & 31;
    A_[r][d] = hg[(size_t)(row0 + r) * 32 + d];
    const int g = row0 + r;
    const int l = g % 60;
    M_[r][d] = (l > 0) ? hbuf[(size_t)(g - 1) * 32 + d] : 0.0f;
  }
  __syncthreads();
  const int rg = tid >> 2;
  const int cg = tid & 3;
  const int c0 = cg * 8;
  const int r0 = rg * 3;
  float acc[3][8];
  #pragma unroll
  for (int i = 0; i < 3; ++i)
    #pragma unroll
    for (int d = 0; d < 8; ++d) acc[i][d] = bnb[c0 + d];
  for (int e = 0; e < cH; ++e) {
    const float4 wn0 = *reinterpret_cast<const float4*>(&wn[e * cH + c0]);
    const float4 wn1 = *reinterpret_cast<const float4*>(&wn[e * cH + c0 + 4]);
    const float4 wr0 = *reinterpret_cast<const float4*>(&wr[e * cH + c0]);
    const float4 wr1 = *reinterpret_cast<const float4*>(&wr[e * cH + c0 + 4]);
    #pragma unroll
    for (int i = 0; i < 3; ++i) {
      const float a = A_[r0 + i][e];
      const float m = M_[r0 + i][e];
      acc[i][0] += a * wn0.x + m * wr0.x; acc[i][1] += a * wn0.y + m * wr0.y;
      acc[i][2] += a * wn0.z + m * wr0.z; acc[i][3] += a * wn0.w + m * wr0.w;
      acc[i][4] += a * wn1.x + m * wr1.x; acc[i][5] += a * wn1.y + m * wr1.y;
      acc[i][6] += a * wn1.z + m * wr1.z; acc[i][7] += a * wn1.w + m * wr1.w;
    }
  }
  __syncthreads();
  #pragma unroll
  for (int i = 0; i < 3; ++i)
    #pragma unroll
    for (int d = 0; d < 8; ++d) A_[r0 + i][c0 + d] = fmaxf(acc[i][d], 0.0f);
  __syncthreads();
  float acc2[3][8];
  #pragma unroll
  for (int i = 0; i < 3; ++i)
    #pragma unroll
    for (int d = 0; d < 8; ++d) acc2[i][d] = b2b[c0 + d];
  for (int e = 0; e < cH; ++e) {
    const float4 w20 = *reinterpret_cast<const float4*>(&w2[e * cH + c0]);
    const float4 w21 = *reinterpret_cast<const float4*>(&w2[e * cH + c0 + 4]);
    #pragma unroll
    for (int i = 0; i < 3; ++i) {
      const float t = A_[r0 + i][e];
      acc2[i][0] += t * w20.x; acc2[i][1] += t * w20.y;
      acc2[i][2] += t * w20.z; acc2[i][3] += t * w20.w;
      acc2[i][4] += t * w21.x; acc2[i][5] += t * w21.y;
      acc2[i][6] += t * w21.z; acc2[i][7] += t * w21.w;
    }
  }
  #pragma unroll
  for (int i = 0; i < 3; ++i)
    #pragma unroll
    for (int d = 0; d < 8; ++d) M_[r0 + i][c0 + d] = acc2[i][d];
  __syncthreads();
  for (int idx = tid; idx < 192 * 32; idx += 256) {
    const int r = idx >> 5, d = idx & 31;
    hg[(size_t)row0 * 32 + idx] = M_[r][d];
  }
}

// ---------------- split-K GEMM (fp32, small): partial[s] = A[:, ks:+64] @ W[ks:+64, n0:+64] ----------------
__global__ __launch_bounds__(256) void gemm_splitk_kernel(
    const float* __restrict__ A, const float* __restrict__ W,
    int K, int N, float* __restrict__ partial) {
  __shared__ __align__(16) float At[128][65];
  __shared__ __align__(16) float Wt[64][64];
  const int tid = threadIdx.x;
  const int n0 = blockIdx.x * 64;
  const int k0 = blockIdx.y * 64;
  const int kw = min(64, K - k0);
  for (int idx = tid; idx < 128 * 64; idx += 256) {
    int r = idx >> 6, kk = idx & 63;
    At[r][kk] = (kk < kw) ? A[(size_t)r * K + k0 + kk] : 0.0f;
  }
  for (int idx = tid; idx < 64 * 64; idx += 256) {
    int kk = idx >> 6, cc = idx & 63;
    Wt[kk][cc] = (kk < kw && n0 + cc < N) ? W[(size_t)(k0 + kk) * N + n0 + cc] : 0.0f;
  }
  __syncthreads();
  const int cg = tid & 15, rg = tid >> 4;
  const int c0 = cg * 4, r0 = rg * 8;
  float acc[8][4];
  #pragma unroll
  for (int i = 0; i < 8; ++i)
    #pragma unroll
    for (int jj = 0; jj < 4; ++jj) acc[i][jj] = 0.0f;
  for (int kk = 0; kk < 64; kk += 2) {
    const float4 wv0 = *reinterpret_cast<const float4*>(&Wt[kk][c0]);
    const float4 wv1 = *reinterpret_cast<const float4*>(&Wt[kk + 1][c0]);
    #pragma unroll
    for (int i = 0; i < 8; ++i) {
      const float2 av = *reinterpret_cast<const float2*>(&At[r0 + i][kk]);
      acc[i][0] += av.x * wv0.x + av.y * wv1.x;
      acc[i][1] += av.x * wv0.y + av.y * wv1.y;
      acc[i][2] += av.x * wv0.z + av.y * wv1.z;
      acc[i][3] += av.x * wv0.w + av.y * wv1.w;
    }
  }
  float* p = partial + (size_t)blockIdx.y * 128 * N;
  #pragma unroll
  for (int i = 0; i < 8; ++i) {
    #pragma unroll
    for (int jj = 0; jj < 4; ++jj) {
      const int cc = n0 + c0 + jj;
      if (cc < N) p[(r0 + i) * N + cc] = acc[i][jj];
    }
  }
}

__global__ __launch_bounds__(256) void mlpred_kernel(
    const float* __restrict__ partial, int S, int N,
    const float* __restrict__ bias, const float* __restrict__ gg,
    const float* __restrict__ bb, const float* __restrict__ mm,
    const float* __restrict__ vv, float* __restrict__ outz) {
  const int oi = blockIdx.x * 256 + threadIdx.x;
  if (oi >= 128 * N) return;
  float s = 0.0f;
  for (int p = 0; p < S; ++p) s += partial[(size_t)p * 128 * N + oi];
  const int c = oi % N;
  const float z = fmaxf(s + bias[c], 0.0f);
  outz[oi] = (z - mm[c]) * rsqrtf(vv[c] + 1e-5f) * gg[c] + bb[c];
}

// bn-epilogue for layer 2 that emits bf16 z2 zero-padded to [128][512] (K pad for MFMA)
__global__ __launch_bounds__(256) void mlpredbf_kernel(
    const float* __restrict__ partial, int S,
    const float* __restrict__ bias, const float* __restrict__ gg,
    const float* __restrict__ bb, const float* __restrict__ mm,
    const float* __restrict__ vv, unsigned short* __restrict__ outbf) {
  const int oi = blockIdx.x * 256 + threadIdx.x;   // over 128*512
  if (oi >= 128 * 512) return;
  const int r = oi >> 9, c = oi & 511;
  unsigned short val = 0;
  if (c < 500) {
    float s = 0.0f;
    for (int p = 0; p < S; ++p) s += partial[(size_t)p * 64000 + r * 500 + c];
    const float z = fmaxf(s + bias[c], 0.0f);
    const float y = (z - mm[c]) * rsqrtf(vv[c] + 1e-5f) * gg[c] + bb[c];
    val = (unsigned short)f2bf(y);
  }
  outbf[oi] = val;
}

// ---------------- big GEMM via bf16 MFMA: h_gcn += z2 @ W3 + b3 (RMW) ----------------
// 765 blocks x (128 rows x 128 cols). 4 waves: wave wv owns cols [wv*32, wv*32+32),
// all 128 rows as 4 M-frags. A (z2bf [128][512], L2-hot) read straight to frags.
// B staged fp32->bf16 via v_cvt_pk into reg-double-buffered LDS, ONE barrier/K-step.
// LDS layout Bs[k-pair][n] u32(bf16 lo=k even, hi=k odd): b128 writes bank-uniform,
// frag reads = 4x ds_read_b32 with bank = lane&31 (2-way = free).
// C/D: col=lane&31, row=(reg&3)+8*(reg>>2)+4*(lane>>5)  [m74/m101 verified]
__global__ __launch_bounds__(256, 3) void w3_mfma_kernel(
    const unsigned short* __restrict__ z2bf, const float* __restrict__ W3,
    const float* __restrict__ b3, float* __restrict__ outh) {
  __shared__ unsigned Bs[2][16][128];
  const int tid = threadIdx.x;
  const int n0 = blockIdx.x * 128;
  const int wv = tid >> 6;
  const int lane = tid & 63;
  const int half = lane >> 5;
  const int lm = lane & 31;
  const int kp = tid >> 4;          // 0..15: staged k-pair
  const int nc = (tid & 15) << 3;   // 0..120: staged n-chunk

  accf16 acc[4] = {};

  const unsigned short* Ab = z2bf + lm * 512 + half * 8;
  const float* Wp = W3 + (size_t)(2 * kp) * cKL32 + n0 + nc;

  // prologue: stage k = 0..31 into buf0 (all rows valid)
  {
    const float4 r0a = *reinterpret_cast<const float4*>(Wp);
    const float4 r0b = *reinterpret_cast<const float4*>(Wp + 4);
    const float4 r1a = *reinterpret_cast<const float4*>(Wp + cKL32);
    const float4 r1b = *reinterpret_cast<const float4*>(Wp + cKL32 + 4);
    uint4v w0 = {pk2bf(r0a.x, r1a.x), pk2bf(r0a.y, r1a.y), pk2bf(r0a.z, r1a.z), pk2bf(r0a.w, r1a.w)};
    uint4v w1 = {pk2bf(r0b.x, r1b.x), pk2bf(r0b.y, r1b.y), pk2bf(r0b.z, r1b.z), pk2bf(r0b.w, r1b.w)};
    *reinterpret_cast<uint4v*>(&Bs[0][kp][nc]) = w0;
    *reinterpret_cast<uint4v*>(&Bs[0][kp][nc + 4]) = w1;
  }
  __syncthreads();

  int cur = 0;
  for (int t = 0; t < 16; ++t) {
    const int k0 = t << 5;
    // (1) A fragments first: MFMA then only needs vmcnt(4) (prefetch stays in flight)
    bfrag8 a0[4], a1[4];
    #pragma unroll
    for (int mf = 0; mf < 4; ++mf) {
      a0[mf] = *reinterpret_cast<const bfrag8*>(Ab + mf * 16384 + k0);
      a1[mf] = *reinterpret_cast<const bfrag8*>(Ab + mf * 16384 + k0 + 16);
    }
    // (2) issue next K-tile W3 loads into registers (hide HBM latency under MFMA)
    float4 r0a = make_float4(0.f, 0.f, 0.f, 0.f), r0b = r0a, r1a = r0a, r1b = r0a;
    if (t < 15) {
      const int kA = k0 + 32 + 2 * kp;
      const float* p = Wp + (size_t)(k0 + 32) * cKL32;
      if (kA < 500)     { r0a = *reinterpret_cast<const float4*>(p);
                          r0b = *reinterpret_cast<const float4*>(p + 4); }
      if (kA + 1 < 500) { r1a = *reinterpret_cast<const float4*>(p + cKL32);
                          r1b = *reinterpret_cast<const float4*>(p + cKL32 + 4); }
    }
    // (3) B fragments from LDS
    const unsigned* Bf = &Bs[cur][0][0];
    const int colL = wv * 32 + lm;
    union { unsigned u[4]; bfrag8 b; } cv0, cv1;
    #pragma unroll
    for (int c = 0; c < 4; ++c) cv0.u[c] = Bf[(half * 4 + c) * 128 + colL];
    #pragma unroll
    for (int c = 0; c < 4; ++c) cv1.u[c] = Bf[(8 + half * 4 + c) * 128 + colL];
    // (4) 8 MFMA
    #pragma unroll
    for (int mf = 0; mf < 4; ++mf)
      acc[mf] = __builtin_amdgcn_mfma_f32_32x32x16_bf16(a0[mf], cv0.b, acc[mf], 0, 0, 0);
    #pragma unroll
    for (int mf = 0; mf < 4; ++mf)
      acc[mf] = __builtin_amdgcn_mfma_f32_32x32x16_bf16(a1[mf], cv1.b, acc[mf], 0, 0, 0);
    // (5) pack + write next buffer, single barrier per K-step
    if (t < 15) {
      uint4v w0 = {pk2bf(r0a.x, r1a.x), pk2bf(r0a.y, r1a.y), pk2bf(r0a.z, r1a.z), pk2bf(r0a.w, r1a.w)};
      uint4v w1 = {pk2bf(r0b.x, r1b.x), pk2bf(r0b.y, r1b.y), pk2bf(r0b.z, r1b.z), pk2bf(r0b.w, r1b.w)};
      *reinterpret_cast<uint4v*>(&Bs[cur ^ 1][kp][nc]) = w0;
      *reinterpret_cast<uint4v*>(&Bs[cur ^ 1][kp][nc + 4]) = w1;
    }
    __syncthreads();
    cur ^= 1;
  }

  const int col = n0 + wv * 32 + lm;
  const float bias = b3[col];
  #pragma unroll
  for (int mf = 0; mf < 4; ++mf) {
    #pragma unroll
    for (int reg = 0; reg < 16; ++reg) {
      const int rr = mf * 32 + (reg & 3) + 8 * (reg >> 2) + 4 * half;
      const size_t o = (size_t)rr * cKL32 + col;
      outh[o] += acc[mf][reg] + bias;
    }
  }
}

// ---------------- ann GEMM split-K ----------------
__global__ __launch_bounds__(256) void ann_kernel(
    const float* __restrict__ hg, const float* __restrict__ annW, float* __restrict__ partial) {
  __shared__ __align__(16) float At[128][34];
  __shared__ __align__(16) float Wt[32][128];
  const int tid = threadIdx.x;
  const int bx = blockIdx.x;   // 255
  const int k0 = bx * 384;
  const int cg = tid & 15, rg = tid >> 4;
  const int c0 = cg * 8, r0 = rg * 8;
  float acc[8][8];
  #pragma unroll
  for (int i = 0; i < 8; ++i)
    #pragma unroll
    for (int jj = 0; jj < 8; ++jj) acc[i][jj] = 0.0f;
  for (int st = 0; st < 12; ++st) {
    const int kb = k0 + st * 32;
    for (int idx = tid; idx < 128 * 32; idx += 256) {
      int r = idx >> 5, kk = idx & 31;
      At[r][kk] = hg[(size_t)r * cKL32 + kb + kk];
    }
    for (int idx = tid; idx < 32 * 128; idx += 256) {
      int kk = idx >> 7, cc2 = idx & 127;
      Wt[kk][cc2] = (cc2 < 100) ? annW[(size_t)(kb + kk) * 100 + cc2] : 0.0f;
    }
    __syncthreads();
    for (int kk = 0; kk < 32; kk += 2) {
      const float4 w00 = *reinterpret_cast<const float4*>(&Wt[kk][c0]);
      const float4 w01 = *reinterpret_cast<const float4*>(&Wt[kk][c0 + 4]);
      const float4 w10 = *reinterpret_cast<const float4*>(&Wt[kk + 1][c0]);
      const float4 w11 = *reinterpret_cast<const float4*>(&Wt[kk + 1][c0 + 4]);
      #pragma unroll
      for (int i = 0; i < 8; ++i) {
        const float2 av = *reinterpret_cast<const float2*>(&At[r0 + i][kk]);
        acc[i][0] += av.x * w00.x + av.y * w10.x;
        acc[i][1] += av.x * w00.y + av.y * w10.y;
        acc[i][2] += av.x * w00.z + av.y * w10.z;
        acc[i][3] += av.x * w00.w + av.y * w10.w;
        acc[i][4] += av.x * w01.x + av.y * w11.x;
        acc[i][5] += av.x * w01.y + av.y * w11.y;
        acc[i][6] += av.x * w01.z + av.y * w11.z;
        acc[i][7] += av.x * w01.w + av.y * w11.w;
      }
    }
    __syncthreads();
  }
  #pragma unroll
  for (int i = 0; i < 8; ++i) {
    #pragma unroll
    for (int jj = 0; jj < 8; ++jj) {
      const int cc = c0 + jj;
      if (cc < 100) partial[(size_t)bx * 12800 + (r0 + i) * 100 + cc] = acc[i][jj];
    }
  }
}

__global__ __launch_bounds__(256) void annred_kernel(
    const float* __restrict__ partial, const float* __restrict__ ab,
    const float* __restrict__ gg, const float* __restrict__ bb,
    const float* __restrict__ mm, const float* __restrict__ vv, float* __restrict__ hid) {
  const int oi = blockIdx.x * 256 + threadIdx.x;   // < 12800
  if (oi < 12800) {
    float s = 0.0f;
    for (int p = 0; p < 255; ++p) s += partial[(size_t)p * 12800 + oi];
    const int c = oi % 100;
    const float z = fmaxf(s + ab[c], 0.0f);
    hid[oi] = (z - mm[c]) * rsqrtf(vv[c] + 1e-5f) * gg[c] + bb[c];
  }
}

// ---------------- log_prob: MAF collapses to u = a*x + b (mask_out all zeros) ----------------
__global__ __launch_bounds__(256) void logp_kernel(
    const float* __restrict__ x, const float* __restrict__ mob,
    const float* __restrict__ mlg, const float* __restrict__ mbeta, float* __restrict__ lp) {
  const int b = blockIdx.x;
  const int tid = threadIdx.x;
  const float rs = rsqrtf(1.0f + 1e-5f);
  const float A0 = __expf(mlg[0] - mob[1]) * rs;
  const float B0 = -mob[0] * __expf(-mob[1]) * __expf(mlg[0]) * rs + mbeta[0];
  const float A1 = __expf(mlg[1] - mob[3]) * rs;
  const float B1 = -mob[2] * __expf(-mob[3]) * __expf(mlg[1]) * rs + mbeta[1];
  const float S = (mlg[0] - mob[1]) + (mlg[1] - mob[3]) - logf(1.0f + 1e-5f);
  const float a = A1 * A0;
  const float bc = A1 * B0 + B1;
  float s = 0.0f;
  for (int t = tid; t < cKL; t += 256) {
    const float u = a * x[b * cKL + t] + bc;
    s += u * u;
  }
  #pragma unroll
  for (int off = 32; off > 0; off >>= 1) s += __shfl_down(s, off);
  __shared__ float red[4];
  if ((tid & 63) == 0) red[tid >> 6] = s;
  __syncthreads();
  if (tid == 0) {
    const float tot = red[0] + red[1] + red[2] + red[3];
    lp[b] = -0.5f * tot / (float)cKL + (-0.5f * kLOG2PI + S);
  }
}

__global__ void lpmean_kernel(const float* __restrict__ lp, float* __restrict__ outm) {
  __shared__ float red[128];
  const int tid = threadIdx.x;
  red[tid] = lp[tid];
  __syncthreads();
  for (int off = 64; off > 0; off >>= 1) {
    if (tid < off) red[tid] += red[tid + off];
    __syncthreads();
  }
  if (tid == 0) outm[0] = red[0] / 128.0f;
}

extern "C" void kernel_launch(void* const* d_in, const int* in_sizes, int n_in,
                              void* d_out, int out_size, void* d_ws, size_t ws_size,
                              hipStream_t stream) {
  const float* x    = (const float*)d_in[0];
  const float* Wq   = (const float*)d_in[1];
  const float* bq   = (const float*)d_in[2];
  const float* Wk   = (const float*)d_in[3];
  const float* bk   = (const float*)d_in[4];
  const float* Wih  = (const float*)d_in[5];
  const float* Whh  = (const float*)d_in[6];
  const float* bih  = (const float*)d_in[7];
  const float* bhh  = (const float*)d_in[8];
  const float* gWn  = (const float*)d_in[9];
  const float* gbn  = (const float*)d_in[10];
  const float* gWr  = (const float*)d_in[11];
  const float* gW2  = (const float*)d_in[12];
  const float* gb2  = (const float*)d_in[13];
  const float* W1   = (const float*)d_in[14];
  const float* b1   = (const float*)d_in[15];
  const float* bn1g = (const float*)d_in[16];
  const float* bn1b = (const float*)d_in[17];
  const float* bn1m = (const float*)d_in[18];
  const float* bn1v = (const float*)d_in[19];
  const float* W2m  = (const float*)d_in[20];
  const float* b2m  = (const float*)d_in[21];
  const float* bn2g = (const float*)d_in[22];
  const float* bn2b = (const float*)d_in[23];
  const float* bn2m = (const float*)d_in[24];
  const float* bn2v = (const float*)d_in[25];
  const float* W3   = (const float*)d_in[26];
  const float* b3   = (const float*)d_in[27];
  const float* annW = (const float*)d_in[28];
  const float* annb = (const float*)d_in[29];
  const float* abg  = (const float*)d_in[30];
  const float* abb  = (const float*)d_in[31];
  const float* abm  = (const float*)d_in[32];
  const float* abv  = (const float*)d_in[33];
  const float* mob  = (const float*)d_in[38];
  const float* mlg  = (const float*)d_in[39];
  const float* mbeta= (const float*)d_in[40];

  float* ws = (float*)d_ws;
  float* qb    = ws;                    // 391680
  float* kb    = ws + 391680;           // 391680
  float* graph = ws + 783360;           // 332928
  float* hbuf  = ws + 1116288;          // 12533760
  float* z1    = ws + 13650048;         // 64000
  unsigned short* z2bf = (unsigned short*)(ws + 13714048);  // 128x512 bf16 (32768 floats of space)
  float* partial = hbuf;                // ann split-K partials (hbuf dead by then)
  float* mp    = hbuf + 4000000;        // mlp split-K partials

  float* outF = (float*)d_out;
  float* hid  = outF;                   // 12800
  float* lpm  = outF + 12800;           // 1
  float* hgcn = outF + 12801;           // 12533760
  float* lp   = outF + 12546561;        // 128

  qk_kernel<<<816, 256, 0, stream>>>(x, Wq, bq, Wk, bk, qb, kb);
  attn_kernel<<<128, 256, 0, stream>>>(qb, kb, graph);
  lstm_kernel<<<1632, 256, 0, stream>>>(x, Wih, Whh, bih, bhh, hbuf);
  agg_kernel<<<dim3(15, 128), 256, 0, stream>>>(hbuf, graph, hgcn);
  gnn2_kernel<<<2040, 256, 0, stream>>>(hbuf, gWn, gbn, gWr, gW2, gb2, hgcn);
  gemm_splitk_kernel<<<dim3(8, 48), 256, 0, stream>>>(x, W1, 3060, 500, mp);
  mlpred_kernel<<<250, 256, 0, stream>>>(mp, 48, 500, b1, bn1g, bn1b, bn1m, bn1v, z1);
  gemm_splitk_kernel<<<dim3(8, 8), 256, 0, stream>>>(z1, W2m, 500, 500, mp);
  mlpredbf_kernel<<<256, 256, 0, stream>>>(mp, 8, b2m, bn2g, bn2b, bn2m, bn2v, z2bf);
  w3_mfma_kernel<<<765, 256, 0, stream>>>(z2bf, W3, b3, hgcn);
  ann_kernel<<<255, 256, 0, stream>>>(hgcn, annW, partial);
  annred_kernel<<<50, 256, 0, stream>>>(partial, annb, abg, abb, abm, abv, hid);
  logp_kernel<<<128, 256, 0, stream>>>(x, mob, mlg, mbeta, lp);
  lpmean_kernel<<<1, 128, 0, stream>>>(lp, lpm);
}

// Round 2
// 860.176 us; speedup vs baseline: 1.3832x; 1.1645x over previous
//
#include <hip/hip_runtime.h>
#include <math.h>

constexpr int cB = 128;
constexpr int cK = 51;
constexpr int cL = 60;
constexpr int cH = 32;
constexpr int cC = 60;           // L*D
constexpr int cKL = 3060;        // K*L
constexpr int cKL32 = 97920;     // K*L*32
constexpr float kLOG2PI = 1.8378770664093453f;

typedef __attribute__((ext_vector_type(8))) short bfrag8;    // 8 bf16 = 4 VGPRs
typedef __attribute__((ext_vector_type(16))) float accf16;   // MFMA 32x32 accumulator
typedef __attribute__((ext_vector_type(4))) unsigned uint4v; // 16B LDS write

__device__ __forceinline__ float fsig(float x) { return 1.0f / (1.0f + __expf(-x)); }
__device__ __forceinline__ float ftanh(float x) {
  float e = __expf(2.0f * x);
  return 1.0f - 2.0f / (e + 1.0f);
}
__device__ __forceinline__ short f2bf(float f) {   // RNE fp32 -> bf16
  union { float f; unsigned u; } v; v.f = f;
  unsigned r = v.u + 0x7FFFu + ((v.u >> 16) & 1u);
  return (short)(r >> 16);
}
__device__ __forceinline__ unsigned pk2bf(float lo, float hi) {  // 2xf32 -> packed 2xbf16 (RNE)
  unsigned r;
  asm("v_cvt_pk_bf16_f32 %0, %1, %2" : "=v"(r) : "v"(lo), "v"(hi));
  return r;
}

// ---------------- q/k projections: rows = B*K = 6528, 8 rows/block ----------------
__global__ __launch_bounds__(256) void qk_kernel(
    const float* __restrict__ x, const float* __restrict__ Wq, const float* __restrict__ bq,
    const float* __restrict__ Wk, const float* __restrict__ bk,
    float* __restrict__ q, float* __restrict__ kx) {
  __shared__ float xs[8][cC];
  const int row0 = blockIdx.x * 8;
  const int tid = threadIdx.x;
  for (int idx = tid; idx < 8 * cC; idx += 256) {
    int lr = idx / cC, t = idx % cC;
    xs[lr][t] = x[(row0 + lr) * cC + t];
  }
  __syncthreads();
  for (int idx = tid; idx < 8 * 2 * cC; idx += 256) {
    int col = idx % cC;
    int r2 = idx / cC;
    int m = r2 & 1, lr = r2 >> 1;
    const float* W = m ? Wk : Wq;
    float acc = m ? bk[col] : bq[col];
    #pragma unroll 4
    for (int t = 0; t < cC; ++t) acc += xs[lr][t] * W[t * cC + col];
    float* outp = m ? kx : q;
    outp[(row0 + lr) * cC + col] = acc;
  }
}

// ---------------- score = q @ reshape(k) / sqrt(60); softmax over axis=1 ----------------
__global__ __launch_bounds__(256) void attn_kernel(
    const float* __restrict__ q, const float* __restrict__ kx, float* __restrict__ graph) {
  __shared__ float qb[cKL];
  __shared__ float kb[cKL];
  __shared__ float sc[cK * cK];
  __shared__ float cmax[cK], csum[cK];
  const int b = blockIdx.x;
  const int tid = threadIdx.x;
  for (int idx = tid; idx < cKL; idx += 256) {
    qb[idx] = q[b * cKL + idx];
    kb[idx] = kx[b * cKL + idx];
  }
  __syncthreads();
  const float scale = 1.0f / sqrtf(60.0f);
  for (int idx = tid; idx < cK * cK; idx += 256) {
    int i = idx / cK, j = idx % cK;
    float acc = 0.0f;
    #pragma unroll 4
    for (int t = 0; t < cC; ++t) acc += qb[i * cC + t] * kb[t * cK + j];
    sc[idx] = acc * scale;
  }
  __syncthreads();
  if (tid < cK) {
    float m = -1e30f;
    for (int i = 0; i < cK; ++i) m = fmaxf(m, sc[i * cK + tid]);
    float ssum = 0.0f;
    for (int i = 0; i < cK; ++i) ssum += __expf(sc[i * cK + tid] - m);
    cmax[tid] = m; csum[tid] = ssum;
  }
  __syncthreads();
  for (int idx = tid; idx < cK * cK; idx += 256) {
    int j = idx % cK;
    graph[b * cK * cK + idx] = __expf(sc[idx] - cmax[j]) / csum[j];
  }
}

// ---------------- LSTM: one wave (64 lanes) per sequence, 4 sequences/block ----------------
__global__ __launch_bounds__(256) void lstm_kernel(
    const float* __restrict__ x, const float* __restrict__ Wih, const float* __restrict__ Whh,
    const float* __restrict__ bih, const float* __restrict__ bhh, float* __restrict__ hout) {
  const int wave = threadIdx.x >> 6;
  const int lane = threadIdx.x & 63;
  const int seq = blockIdx.x * 4 + wave;   // < 6528
  const int j = lane;
  float w0[32], w1[32];
  #pragma unroll
  for (int k2 = 0; k2 < 32; ++k2) {
    w0[k2] = Whh[j * 32 + k2];
    w1[k2] = Whh[(j + 64) * 32 + k2];
  }
  const float wi0 = Wih[j], wi1 = Wih[j + 64];
  const float bb0 = bih[j] + bhh[j];
  const float bb1 = bih[j + 64] + bhh[j + 64];
  const float xr = (lane < cL) ? x[seq * cL + lane] : 0.0f;
  float h = 0.0f, c = 0.0f;
  float* outp = hout + (size_t)seq * cL * cH;
  for (int t = 0; t < cL; ++t) {
    const float xt = __shfl(xr, t);
    float a0 = bb0 + wi0 * xt;
    float a1 = bb1 + wi1 * xt;
    #pragma unroll
    for (int k2 = 0; k2 < 32; ++k2) {
      const float hk = __shfl(h, k2);
      a0 += w0[k2] * hk;
      a1 += w1[k2] * hk;
    }
    const float sA = fsig(a0);
    const float sB = fsig(a1);
    const float tB = ftanh(a1);
    const float p = sA * tB;
    const float sf = __shfl(sA, (lane & 31) + 32);
    const float so = __shfl(sB, (lane & 31) + 32);
    c = sf * c + p;
    h = so * ftanh(c);
    if (lane < 32) outp[t * cH + lane] = h;
  }
}

// ---------------- agg: per b, agg = G^T (51x51) @ H (51x1920), 128-col tiles ----------------
__global__ __launch_bounds__(256) void agg_kernel(
    const float* __restrict__ hbuf, const float* __restrict__ graph,
    float* __restrict__ aggout) {
  __shared__ float G[cK * cK];
  __shared__ __align__(16) float Ht[cK][128];
  const int b = blockIdx.y;
  const int c0 = blockIdx.x * 128;
  const int tid = threadIdx.x;
  for (int idx = tid; idx < cK * cK; idx += 256) G[idx] = graph[b * cK * cK + idx];
  for (int idx = tid; idx < cK * 128; idx += 256) {
    int k = idx >> 7, c = idx & 127;
    Ht[k][c] = hbuf[((size_t)b * cK + k) * 1920 + c0 + c];
  }
  __syncthreads();
  const int jg = tid >> 5;
  const int cg = tid & 31;
  const int cc = cg * 4;
  float4 acc[7];
  #pragma unroll
  for (int jj = 0; jj < 7; ++jj) acc[jj] = make_float4(0.f, 0.f, 0.f, 0.f);
  for (int k = 0; k < cK; ++k) {
    const float4 hv = *reinterpret_cast<const float4*>(&Ht[k][cc]);
    #pragma unroll
    for (int jj = 0; jj < 7; ++jj) {
      const int j = jg + jj * 8;
      const float g = (j < cK) ? G[k * cK + j] : 0.0f;
      acc[jj].x += g * hv.x; acc[jj].y += g * hv.y;
      acc[jj].z += g * hv.z; acc[jj].w += g * hv.w;
    }
  }
  #pragma unroll
  for (int jj = 0; jj < 7; ++jj) {
    const int j = jg + jj * 8;
    if (j < cK) {
      const size_t o = ((size_t)b * cK + j) * 1920 + c0 + cc;
      aggout[o + 0] = acc[jj].x; aggout[o + 1] = acc[jj].y;
      aggout[o + 2] = acc[jj].z; aggout[o + 3] = acc[jj].w;
    }
  }
}

// ---------------- gnn2: per-row h_gcn_pre = relu(agg@Wn + bn + hm@Wr) @ W2 + b2 ----------------
__global__ __launch_bounds__(256) void gnn2_kernel(
    const float* __restrict__ hbuf, const float* __restrict__ Wn,
    const float* __restrict__ bn_, const float* __restrict__ Wr,
    const float* __restrict__ W2, const float* __restrict__ b2,
    float* __restrict__ hg) {
  __shared__ __align__(16) float wn[cH * cH];
  __shared__ __align__(16) float wr[cH * cH];
  __shared__ __align__(16) float w2[cH * cH];
  __shared__ float bnb[cH], b2b[cH];
  __shared__ float A_[192][33];
  __shared__ float M_[192][33];
  const int tid = threadIdx.x;
  const int row0 = blockIdx.x * 192;
  for (int idx = tid; idx < cH * cH; idx += 256) { wn[idx] = Wn[idx]; wr[idx] = Wr[idx]; w2[idx] = W2[idx]; }
  if (tid < cH) { bnb[tid] = bn_[tid]; b2b[tid] = b2[tid]; }
  for (int idx = tid; idx < 192 * 32; idx += 256) {
    const int r = idx >> 5, d = idx & 31;
    A_[r][d] = hg[(size_t)(row0 + r) * 32 + d];
    const int g = row0 + r;
    const int l = g % 60;
    M_[r][d] = (l > 0) ? hbuf[(size_t)(g - 1) * 32 + d] : 0.0f;
  }
  __syncthreads();
  const int rg = tid >> 2;
  const int cg = tid & 3;
  const int c0 = cg * 8;
  const int r0 = rg * 3;
  float acc[3][8];
  #pragma unroll
  for (int i = 0; i < 3; ++i)
    #pragma unroll
    for (int d = 0; d < 8; ++d) acc[i][d] = bnb[c0 + d];
  for (int e = 0; e < cH; ++e) {
    const float4 wn0 = *reinterpret_cast<const float4*>(&wn[e * cH + c0]);
    const float4 wn1 = *reinterpret_cast<const float4*>(&wn[e * cH + c0 + 4]);
    const float4 wr0 = *reinterpret_cast<const float4*>(&wr[e * cH + c0]);
    const float4 wr1 = *reinterpret_cast<const float4*>(&wr[e * cH + c0 + 4]);
    #pragma unroll
    for (int i = 0; i < 3; ++i) {
      const float a = A_[r0 + i][e];
      const float m = M_[r0 + i][e];
      acc[i][0] += a * wn0.x + m * wr0.x; acc[i][1] += a * wn0.y + m * wr0.y;
      acc[i][2] += a * wn0.z + m * wr0.z; acc[i][3] += a * wn0.w + m * wr0.w;
      acc[i][4] += a * wn1.x + m * wr1.x; acc[i][5] += a * wn1.y + m * wr1.y;
      acc[i][6] += a * wn1.z + m * wr1.z; acc[i][7] += a * wn1.w + m * wr1.w;
    }
  }
  __syncthreads();
  #pragma unroll
  for (int i = 0; i < 3; ++i)
    #pragma unroll
    for (int d = 0; d < 8; ++d) A_[r0 + i][c0 + d] = fmaxf(acc[i][d], 0.0f);
  __syncthreads();
  float acc2[3][8];
  #pragma unroll
  for (int i = 0; i < 3; ++i)
    #pragma unroll
    for (int d = 0; d < 8; ++d) acc2[i][d] = b2b[c0 + d];
  for (int e = 0; e < cH; ++e) {
    const float4 w20 = *reinterpret_cast<const float4*>(&w2[e * cH + c0]);
    const float4 w21 = *reinterpret_cast<const float4*>(&w2[e * cH + c0 + 4]);
    #pragma unroll
    for (int i = 0; i < 3; ++i) {
      const float t = A_[r0 + i][e];
      acc2[i][0] += t * w20.x; acc2[i][1] += t * w20.y;
      acc2[i][2] += t * w20.z; acc2[i][3] += t * w20.w;
      acc2[i][4] += t * w21.x; acc2[i][5] += t * w21.y;
      acc2[i][6] += t * w21.z; acc2[i][7] += t * w21.w;
    }
  }
  #pragma unroll
  for (int i = 0; i < 3; ++i)
    #pragma unroll
    for (int d = 0; d < 8; ++d) M_[r0 + i][c0 + d] = acc2[i][d];
  __syncthreads();
  for (int idx = tid; idx < 192 * 32; idx += 256) {
    const int r = idx >> 5, d = idx & 31;
    hg[(size_t)row0 * 32 + idx] = M_[r][d];
  }
}

// ---------------- split-K GEMM (fp32, small): partial[s] = A[:, ks:+64] @ W[ks:+64, n0:+64] ----------------
__global__ __launch_bounds__(256) void gemm_splitk_kernel(
    const float* __restrict__ A, const float* __restrict__ W,
    int K, int N, float* __restrict__ partial) {
  __shared__ __align__(16) float At[128][65];
  __shared__ __align__(16) float Wt[64][64];
  const int tid = threadIdx.x;
  const int n0 = blockIdx.x * 64;
  const int k0 = blockIdx.y * 64;
  const int kw = min(64, K - k0);
  for (int idx = tid; idx < 128 * 64; idx += 256) {
    int r = idx >> 6, kk = idx & 63;
    At[r][kk] = (kk < kw) ? A[(size_t)r * K + k0 + kk] : 0.0f;
  }
  for (int idx = tid; idx < 64 * 64; idx += 256) {
    int kk = idx >> 6, cc = idx & 63;
    Wt[kk][cc] = (kk < kw && n0 + cc < N) ? W[(size_t)(k0 + kk) * N + n0 + cc] : 0.0f;
  }
  __syncthreads();
  const int cg = tid & 15, rg = tid >> 4;
  const int c0 = cg * 4, r0 = rg * 8;
  float acc[8][4];
  #pragma unroll
  for (int i = 0; i < 8; ++i)
    #pragma unroll
    for (int jj = 0; jj < 4; ++jj) acc[i][jj] = 0.0f;
  for (int kk = 0; kk < 64; kk += 2) {
    const float4 wv0 = *reinterpret_cast<const float4*>(&Wt[kk][c0]);
    const float4 wv1 = *reinterpret_cast<const float4*>(&Wt[kk + 1][c0]);
    #pragma unroll
    for (int i = 0; i < 8; ++i) {
      const float2 av = *reinterpret_cast<const float2*>(&At[r0 + i][kk]);
      acc[i][0] += av.x * wv0.x + av.y * wv1.x;
      acc[i][1] += av.x * wv0.y + av.y * wv1.y;
      acc[i][2] += av.x * wv0.z + av.y * wv1.z;
      acc[i][3] += av.x * wv0.w + av.y * wv1.w;
    }
  }
  float* p = partial + (size_t)blockIdx.y * 128 * N;
  #pragma unroll
  for (int i = 0; i < 8; ++i) {
    #pragma unroll
    for (int jj = 0; jj < 4; ++jj) {
      const int cc = n0 + c0 + jj;
      if (cc < N) p[(r0 + i) * N + cc] = acc[i][jj];
    }
  }
}

__global__ __launch_bounds__(256) void mlpred_kernel(
    const float* __restrict__ partial, int S, int N,
    const float* __restrict__ bias, const float* __restrict__ gg,
    const float* __restrict__ bb, const float* __restrict__ mm,
    const float* __restrict__ vv, float* __restrict__ outz) {
  const int oi = blockIdx.x * 256 + threadIdx.x;
  if (oi >= 128 * N) return;
  float s = 0.0f;
  for (int p = 0; p < S; ++p) s += partial[(size_t)p * 128 * N + oi];
  const int c = oi % N;
  const float z = fmaxf(s + bias[c], 0.0f);
  outz[oi] = (z - mm[c]) * rsqrtf(vv[c] + 1e-5f) * gg[c] + bb[c];
}

// bn-epilogue for layer 2 that emits bf16 z2 zero-padded to [128][512] (K pad for MFMA)
__global__ __launch_bounds__(256) void mlpredbf_kernel(
    const float* __restrict__ partial, int S,
    const float* __restrict__ bias, const float* __restrict__ gg,
    const float* __restrict__ bb, const float* __restrict__ mm,
    const float* __restrict__ vv, unsigned short* __restrict__ outbf) {
  const int oi = blockIdx.x * 256 + threadIdx.x;   // over 128*512
  if (oi >= 128 * 512) return;
  const int r = oi >> 9, c = oi & 511;
  unsigned short val = 0;
  if (c < 500) {
    float s = 0.0f;
    for (int p = 0; p < S; ++p) s += partial[(size_t)p * 64000 + r * 500 + c];
    const float z = fmaxf(s + bias[c], 0.0f);
    const float y = (z - mm[c]) * rsqrtf(vv[c] + 1e-5f) * gg[c] + bb[c];
    val = (unsigned short)f2bf(y);
  }
  outbf[oi] = val;
}

// ---------------- big GEMM via bf16 MFMA: h_gcn += z2 @ W3 + b3 (RMW) ----------------
// 765 blocks x (128 rows x 128 cols). 4 waves: wave wv owns cols [wv*32, wv*32+32),
// all 128 rows as 4 M-frags. A (z2bf [128][512], L2-hot) read straight to frags.
// B staged fp32->bf16 via v_cvt_pk into reg-double-buffered LDS, ONE barrier/K-step.
// LDS layout Bs[k-pair][n] u32(bf16 lo=k even, hi=k odd): b128 writes bank-uniform,
// frag reads = 4x ds_read_b32 with bank = lane&31 (2-way = free).
// C/D: col=lane&31, row=(reg&3)+8*(reg>>2)+4*(lane>>5)  [m74/m101 verified]
__global__ __launch_bounds__(256, 3) void w3_mfma_kernel(
    const unsigned short* __restrict__ z2bf, const float* __restrict__ W3,
    const float* __restrict__ b3, float* __restrict__ outh) {
  __shared__ unsigned Bs[2][16][128];
  const int tid = threadIdx.x;
  const int n0 = blockIdx.x * 128;
  const int wv = tid >> 6;
  const int lane = tid & 63;
  const int half = lane >> 5;
  const int lm = lane & 31;
  const int kp = tid >> 4;          // 0..15: staged k-pair
  const int nc = (tid & 15) << 3;   // 0..120: staged n-chunk

  accf16 acc[4] = {};

  const unsigned short* Ab = z2bf + lm * 512 + half * 8;
  const float* Wp = W3 + (size_t)(2 * kp) * cKL32 + n0 + nc;

  // prologue: stage k = 0..31 into buf0 (all rows valid)
  {
    const float4 r0a = *reinterpret_cast<const float4*>(Wp);
    const float4 r0b = *reinterpret_cast<const float4*>(Wp + 4);
    const float4 r1a = *reinterpret_cast<const float4*>(Wp + cKL32);
    const float4 r1b = *reinterpret_cast<const float4*>(Wp + cKL32 + 4);
    uint4v w0 = {pk2bf(r0a.x, r1a.x), pk2bf(r0a.y, r1a.y), pk2bf(r0a.z, r1a.z), pk2bf(r0a.w, r1a.w)};
    uint4v w1 = {pk2bf(r0b.x, r1b.x), pk2bf(r0b.y, r1b.y), pk2bf(r0b.z, r1b.z), pk2bf(r0b.w, r1b.w)};
    *reinterpret_cast<uint4v*>(&Bs[0][kp][nc]) = w0;
    *reinterpret_cast<uint4v*>(&Bs[0][kp][nc + 4]) = w1;
  }
  __syncthreads();

  int cur = 0;
  for (int t = 0; t < 16; ++t) {
    const int k0 = t << 5;
    // (1) A fragments first: MFMA then only needs vmcnt(4) (prefetch stays in flight)
    bfrag8 a0[4], a1[4];
    #pragma unroll
    for (int mf = 0; mf < 4; ++mf) {
      a0[mf] = *reinterpret_cast<const bfrag8*>(Ab + mf * 16384 + k0);
      a1[mf] = *reinterpret_cast<const bfrag8*>(Ab + mf * 16384 + k0 + 16);
    }
    // (2) issue next K-tile W3 loads into registers (hide HBM latency under MFMA)
    float4 r0a = make_float4(0.f, 0.f, 0.f, 0.f), r0b = r0a, r1a = r0a, r1b = r0a;
    if (t < 15) {
      const int kA = k0 + 32 + 2 * kp;
      const float* p = Wp + (size_t)(k0 + 32) * cKL32;
      if (kA < 500)     { r0a = *reinterpret_cast<const float4*>(p);
                          r0b = *reinterpret_cast<const float4*>(p + 4); }
      if (kA + 1 < 500) { r1a = *reinterpret_cast<const float4*>(p + cKL32);
                          r1b = *reinterpret_cast<const float4*>(p + cKL32 + 4); }
    }
    // (3) B fragments from LDS
    const unsigned* Bf = &Bs[cur][0][0];
    const int colL = wv * 32 + lm;
    union { unsigned u[4]; bfrag8 b; } cv0, cv1;
    #pragma unroll
    for (int c = 0; c < 4; ++c) cv0.u[c] = Bf[(half * 4 + c) * 128 + colL];
    #pragma unroll
    for (int c = 0; c < 4; ++c) cv1.u[c] = Bf[(8 + half * 4 + c) * 128 + colL];
    // (4) 8 MFMA
    #pragma unroll
    for (int mf = 0; mf < 4; ++mf)
      acc[mf] = __builtin_amdgcn_mfma_f32_32x32x16_bf16(a0[mf], cv0.b, acc[mf], 0, 0, 0);
    #pragma unroll
    for (int mf = 0; mf < 4; ++mf)
      acc[mf] = __builtin_amdgcn_mfma_f32_32x32x16_bf16(a1[mf], cv1.b, acc[mf], 0, 0, 0);
    // (5) pack + write next buffer, single barrier per K-step
    if (t < 15) {
      uint4v w0 = {pk2bf(r0a.x, r1a.x), pk2bf(r0a.y, r1a.y), pk2bf(r0a.z, r1a.z), pk2bf(r0a.w, r1a.w)};
      uint4v w1 = {pk2bf(r0b.x, r1b.x), pk2bf(r0b.y, r1b.y), pk2bf(r0b.z, r1b.z), pk2bf(r0b.w, r1b.w)};
      *reinterpret_cast<uint4v*>(&Bs[cur ^ 1][kp][nc]) = w0;
      *reinterpret_cast<uint4v*>(&Bs[cur ^ 1][kp][nc + 4]) = w1;
    }
    __syncthreads();
    cur ^= 1;
  }

  const int col = n0 + wv * 32 + lm;
  const float bias = b3[col];
  #pragma unroll
  for (int mf = 0; mf < 4; ++mf) {
    #pragma unroll
    for (int reg = 0; reg < 16; ++reg) {
      const int rr = mf * 32 + (reg & 3) + 8 * (reg >> 2) + 4 * half;
      const size_t o = (size_t)rr * cKL32 + col;
      outh[o] += acc[mf][reg] + bias;
    }
  }
}

// ---------------- ann GEMM via bf16 MFMA, split-K x765 ----------------
// partial[bx] = hg[0:128, kb:kb+128] @ annW[kb:kb+128, 0:100]  (kb = bx*128)
// Same structure as w3: 4 waves x 32 cols (cols 100..127 dead), 4 M-frags.
// A (hgcn, L3-hot) loaded direct to frags with on-the-fly cvt_pk.
// B (annW) staged via reg-double-buffered Bs k-pair layout; one barrier/K-step.
__global__ __launch_bounds__(256, 3) void ann_mfma_kernel(
    const float* __restrict__ hg, const float* __restrict__ annW,
    float* __restrict__ partial) {
  __shared__ unsigned Bs[2][16][128];
  const int tid = threadIdx.x;
  const int bx = blockIdx.x;          // 765
  const int kbase = bx * 128;
  const int wv = tid >> 6;
  const int lane = tid & 63;
  const int half = lane >> 5;
  const int lm = lane & 31;

  accf16 acc[4] = {};

  // prologue: stage k-pairs of [kbase, kbase+32) into buf0
  #pragma unroll
  for (int i = 0; i < 8; ++i) {
    const int idx = tid + i * 256;          // 0..2047
    const int kp = idx >> 7, col = idx & 127;
    float w0 = 0.f, w1 = 0.f;
    if (col < 100) {
      const size_t base = (size_t)(kbase + 2 * kp) * 100 + col;
      w0 = annW[base];
      w1 = annW[base + 100];
    }
    Bs[0][kp][col] = pk2bf(w0, w1);
  }
  __syncthreads();

  const float* Ap = hg + (size_t)lm * cKL32 + kbase + half * 8;
  int cur = 0;
  for (int t = 0; t < 4; ++t) {
    const int k0 = t * 32;
    // (1) A fragments: direct global fp32 loads + cvt (L3-resident hgcn)
    bfrag8 a0[4], a1[4];
    #pragma unroll
    for (int mf = 0; mf < 4; ++mf) {
      const float* p = Ap + (size_t)mf * 32 * cKL32 + k0;
      const float4 f0 = *reinterpret_cast<const float4*>(p);
      const float4 f1 = *reinterpret_cast<const float4*>(p + 4);
      const float4 g0 = *reinterpret_cast<const float4*>(p + 16);
      const float4 g1 = *reinterpret_cast<const float4*>(p + 20);
      union { unsigned u[4]; bfrag8 b; } ua, ub;
      ua.u[0] = pk2bf(f0.x, f0.y); ua.u[1] = pk2bf(f0.z, f0.w);
      ua.u[2] = pk2bf(f1.x, f1.y); ua.u[3] = pk2bf(f1.z, f1.w);
      ub.u[0] = pk2bf(g0.x, g0.y); ub.u[1] = pk2bf(g0.z, g0.w);
      ub.u[2] = pk2bf(g1.x, g1.y); ub.u[3] = pk2bf(g1.z, g1.w);
      a0[mf] = ua.b; a1[mf] = ub.b;
    }
    // (2) prefetch next 32-k slab of annW into registers
    float w0r[8], w1r[8];
    if (t < 3) {
      #pragma unroll
      for (int i = 0; i < 8; ++i) {
        const int idx = tid + i * 256;
        const int kp = idx >> 7, col = idx & 127;
        w0r[i] = 0.f; w1r[i] = 0.f;
        if (col < 100) {
          const size_t base = (size_t)(kbase + (t + 1) * 32 + 2 * kp) * 100 + col;
          w0r[i] = annW[base];
          w1r[i] = annW[base + 100];
        }
      }
    }
    // (3) B fragments from LDS
    const unsigned* Bf = &Bs[cur][0][0];
    const int colL = wv * 32 + lm;
    union { unsigned u[4]; bfrag8 b; } cv0, cv1;
    #pragma unroll
    for (int c = 0; c < 4; ++c) cv0.u[c] = Bf[(half * 4 + c) * 128 + colL];
    #pragma unroll
    for (int c = 0; c < 4; ++c) cv1.u[c] = Bf[(8 + half * 4 + c) * 128 + colL];
    // (4) 8 MFMA
    #pragma unroll
    for (int mf = 0; mf < 4; ++mf)
      acc[mf] = __builtin_amdgcn_mfma_f32_32x32x16_bf16(a0[mf], cv0.b, acc[mf], 0, 0, 0);
    #pragma unroll
    for (int mf = 0; mf < 4; ++mf)
      acc[mf] = __builtin_amdgcn_mfma_f32_32x32x16_bf16(a1[mf], cv1.b, acc[mf], 0, 0, 0);
    // (5) pack + write next buffer
    if (t < 3) {
      #pragma unroll
      for (int i = 0; i < 8; ++i) {
        const int idx = tid + i * 256;
        const int kp = idx >> 7, col = idx & 127;
        Bs[cur ^ 1][kp][col] = pk2bf(w0r[i], w1r[i]);
      }
    }
    __syncthreads();
    cur ^= 1;
  }

  const int col = wv * 32 + lm;
  if (col < 100) {
    float* p = partial + (size_t)bx * 12800;
    #pragma unroll
    for (int mf = 0; mf < 4; ++mf) {
      #pragma unroll
      for (int reg = 0; reg < 16; ++reg) {
        const int rr = mf * 32 + (reg & 3) + 8 * (reg >> 2) + 4 * half;
        p[rr * 100 + col] = acc[mf][reg];
      }
    }
  }
}

// stage-1 reduction: partial2[by] = sum of 51 partials (15 groups x 51 = 765)
__global__ __launch_bounds__(256) void annred1_kernel(
    const float* __restrict__ partial, float* __restrict__ partial2) {
  const int oi = blockIdx.x * 256 + threadIdx.x;   // < 12800
  const int by = blockIdx.y;                        // 15
  if (oi >= 12800) return;
  const float* p = partial + (size_t)(by * 51) * 12800 + oi;
  float s = 0.0f;
  #pragma unroll 4
  for (int q = 0; q < 51; ++q) s += p[(size_t)q * 12800];
  partial2[(size_t)by * 12800 + oi] = s;
}

// stage-2: sum 15 groups + bias + relu + BN
__global__ __launch_bounds__(256) void annred2_kernel(
    const float* __restrict__ partial2, const float* __restrict__ ab,
    const float* __restrict__ gg, const float* __restrict__ bb,
    const float* __restrict__ mm, const float* __restrict__ vv, float* __restrict__ hid) {
  const int oi = blockIdx.x * 256 + threadIdx.x;   // < 12800
  if (oi < 12800) {
    float s = 0.0f;
    #pragma unroll
    for (int p = 0; p < 15; ++p) s += partial2[(size_t)p * 12800 + oi];
    const int c = oi % 100;
    const float z = fmaxf(s + ab[c], 0.0f);
    hid[oi] = (z - mm[c]) * rsqrtf(vv[c] + 1e-5f) * gg[c] + bb[c];
  }
}

// ---------------- log_prob: MAF collapses to u = a*x + b (mask_out all zeros) ----------------
__global__ __launch_bounds__(256) void logp_kernel(
    const float* __restrict__ x, const float* __restrict__ mob,
    const float* __restrict__ mlg, const float* __restrict__ mbeta, float* __restrict__ lp) {
  const int b = blockIdx.x;
  const int tid = threadIdx.x;
  const float rs = rsqrtf(1.0f + 1e-5f);
  const float A0 = __expf(mlg[0] - mob[1]) * rs;
  const float B0 = -mob[0] * __expf(-mob[1]) * __expf(mlg[0]) * rs + mbeta[0];
  const float A1 = __expf(mlg[1] - mob[3]) * rs;
  const float B1 = -mob[2] * __expf(-mob[3]) * __expf(mlg[1]) * rs + mbeta[1];
  const float S = (mlg[0] - mob[1]) + (mlg[1] - mob[3]) - logf(1.0f + 1e-5f);
  const float a = A1 * A0;
  const float bc = A1 * B0 + B1;
  float s = 0.0f;
  for (int t = tid; t < cKL; t += 256) {
    const float u = a * x[b * cKL + t] + bc;
    s += u * u;
  }
  #pragma unroll
  for (int off = 32; off > 0; off >>= 1) s += __shfl_down(s, off);
  __shared__ float red[4];
  if ((tid & 63) == 0) red[tid >> 6] = s;
  __syncthreads();
  if (tid == 0) {
    const float tot = red[0] + red[1] + red[2] + red[3];
    lp[b] = -0.5f * tot / (float)cKL + (-0.5f * kLOG2PI + S);
  }
}

__global__ void lpmean_kernel(const float* __restrict__ lp, float* __restrict__ outm) {
  __shared__ float red[128];
  const int tid = threadIdx.x;
  red[tid] = lp[tid];
  __syncthreads();
  for (int off = 64; off > 0; off >>= 1) {
    if (tid < off) red[tid] += red[tid + off];
    __syncthreads();
  }
  if (tid == 0) outm[0] = red[0] / 128.0f;
}

extern "C" void kernel_launch(void* const* d_in, const int* in_sizes, int n_in,
                              void* d_out, int out_size, void* d_ws, size_t ws_size,
                              hipStream_t stream) {
  const float* x    = (const float*)d_in[0];
  const float* Wq   = (const float*)d_in[1];
  const float* bq   = (const float*)d_in[2];
  const float* Wk   = (const float*)d_in[3];
  const float* bk   = (const float*)d_in[4];
  const float* Wih  = (const float*)d_in[5];
  const float* Whh  = (const float*)d_in[6];
  const float* bih  = (const float*)d_in[7];
  const float* bhh  = (const float*)d_in[8];
  const float* gWn  = (const float*)d_in[9];
  const float* gbn  = (const float*)d_in[10];
  const float* gWr  = (const float*)d_in[11];
  const float* gW2  = (const float*)d_in[12];
  const float* gb2  = (const float*)d_in[13];
  const float* W1   = (const float*)d_in[14];
  const float* b1   = (const float*)d_in[15];
  const float* bn1g = (const float*)d_in[16];
  const float* bn1b = (const float*)d_in[17];
  const float* bn1m = (const float*)d_in[18];
  const float* bn1v = (const float*)d_in[19];
  const float* W2m  = (const float*)d_in[20];
  const float* b2m  = (const float*)d_in[21];
  const float* bn2g = (const float*)d_in[22];
  const float* bn2b = (const float*)d_in[23];
  const float* bn2m = (const float*)d_in[24];
  const float* bn2v = (const float*)d_in[25];
  const float* W3   = (const float*)d_in[26];
  const float* b3   = (const float*)d_in[27];
  const float* annW = (const float*)d_in[28];
  const float* annb = (const float*)d_in[29];
  const float* abg  = (const float*)d_in[30];
  const float* abb  = (const float*)d_in[31];
  const float* abm  = (const float*)d_in[32];
  const float* abv  = (const float*)d_in[33];
  const float* mob  = (const float*)d_in[38];
  const float* mlg  = (const float*)d_in[39];
  const float* mbeta= (const float*)d_in[40];

  float* ws = (float*)d_ws;
  float* qb    = ws;                    // 391680
  float* kb    = ws + 391680;           // 391680
  float* graph = ws + 783360;           // 332928
  float* hbuf  = ws + 1116288;          // 12533760
  float* z1    = ws + 13650048;         // 64000
  unsigned short* z2bf = (unsigned short*)(ws + 13714048);  // 128x512 bf16
  float* partial  = hbuf;               // ann split-K partials: 765*12800 = 9.79M floats
  float* partial2 = hbuf + 10000000;    // 15*12800 = 192000 floats
  float* mp    = hbuf + 4000000;        // mlp split-K partials (dead before ann)

  float* outF = (float*)d_out;
  float* hid  = outF;                   // 12800
  float* lpm  = outF + 12800;           // 1
  float* hgcn = outF + 12801;           // 12533760
  float* lp   = outF + 12546561;        // 128

  qk_kernel<<<816, 256, 0, stream>>>(x, Wq, bq, Wk, bk, qb, kb);
  attn_kernel<<<128, 256, 0, stream>>>(qb, kb, graph);
  lstm_kernel<<<1632, 256, 0, stream>>>(x, Wih, Whh, bih, bhh, hbuf);
  agg_kernel<<<dim3(15, 128), 256, 0, stream>>>(hbuf, graph, hgcn);
  gnn2_kernel<<<2040, 256, 0, stream>>>(hbuf, gWn, gbn, gWr, gW2, gb2, hgcn);
  gemm_splitk_kernel<<<dim3(8, 48), 256, 0, stream>>>(x, W1, 3060, 500, mp);
  mlpred_kernel<<<250, 256, 0, stream>>>(mp, 48, 500, b1, bn1g, bn1b, bn1m, bn1v, z1);
  gemm_splitk_kernel<<<dim3(8, 8), 256, 0, stream>>>(z1, W2m, 500, 500, mp);
  mlpredbf_kernel<<<256, 256, 0, stream>>>(mp, 8, b2m, bn2g, bn2b, bn2m, bn2v, z2bf);
  w3_mfma_kernel<<<765, 256, 0, stream>>>(z2bf, W3, b3, hgcn);
  ann_mfma_kernel<<<765, 256, 0, stream>>>(hgcn, annW, partial);
  annred1_kernel<<<dim3(50, 15), 256, 0, stream>>>(partial, partial2);
  annred2_kernel<<<50, 256, 0, stream>>>(partial2, annb, abg, abb, abm, abv, hid);
  logp_kernel<<<128, 256, 0, stream>>>(x, mob, mlg, mbeta, lp);
  lpmean_kernel<<<1, 128, 0, stream>>>(lp, lpm);
}

// Round 3
// 780.114 us; speedup vs baseline: 1.5252x; 1.1026x over previous
//
#include <hip/hip_runtime.h>
#include <math.h>

constexpr int cB = 128;
constexpr int cK = 51;
constexpr int cL = 60;
constexpr int cH = 32;
constexpr int cC = 60;           // L*D
constexpr int cKL = 3060;        // K*L
constexpr int cKL32 = 97920;     // K*L*32
constexpr float kLOG2PI = 1.8378770664093453f;

typedef __attribute__((ext_vector_type(8))) short bfrag8;    // 8 bf16 = 4 VGPRs
typedef __attribute__((ext_vector_type(16))) float accf16;   // MFMA 32x32 accumulator
typedef __attribute__((ext_vector_type(4))) unsigned uint4v; // 16B LDS write

__device__ __forceinline__ float frcp(float x) { return __builtin_amdgcn_rcpf(x); }
__device__ __forceinline__ float fsig(float x) { return frcp(1.0f + __expf(-x)); }
__device__ __forceinline__ float ftanh(float x) {
  float e = __expf(2.0f * x);
  return 1.0f - 2.0f * frcp(e + 1.0f);
}
__device__ __forceinline__ float rdlane(float v, int k) {
  return __uint_as_float(__builtin_amdgcn_readlane(__float_as_uint(v), k));
}
__device__ __forceinline__ short f2bf(float f) {   // RNE fp32 -> bf16
  union { float f; unsigned u; } v; v.f = f;
  unsigned r = v.u + 0x7FFFu + ((v.u >> 16) & 1u);
  return (short)(r >> 16);
}
__device__ __forceinline__ unsigned pk2bf(float lo, float hi) {  // 2xf32 -> packed 2xbf16 (RNE)
  unsigned r;
  asm("v_cvt_pk_bf16_f32 %0, %1, %2" : "=v"(r) : "v"(lo), "v"(hi));
  return r;
}

// ---------------- q/k projections: rows = B*K = 6528, 8 rows/block ----------------
__global__ __launch_bounds__(256) void qk_kernel(
    const float* __restrict__ x, const float* __restrict__ Wq, const float* __restrict__ bq,
    const float* __restrict__ Wk, const float* __restrict__ bk,
    float* __restrict__ q, float* __restrict__ kx) {
  __shared__ float xs[8][cC];
  const int row0 = blockIdx.x * 8;
  const int tid = threadIdx.x;
  for (int idx = tid; idx < 8 * cC; idx += 256) {
    int lr = idx / cC, t = idx % cC;
    xs[lr][t] = x[(row0 + lr) * cC + t];
  }
  __syncthreads();
  for (int idx = tid; idx < 8 * 2 * cC; idx += 256) {
    int col = idx % cC;
    int r2 = idx / cC;
    int m = r2 & 1, lr = r2 >> 1;
    const float* W = m ? Wk : Wq;
    float acc = m ? bk[col] : bq[col];
    #pragma unroll 4
    for (int t = 0; t < cC; ++t) acc += xs[lr][t] * W[t * cC + col];
    float* outp = m ? kx : q;
    outp[(row0 + lr) * cC + col] = acc;
  }
}

// ---------------- score = q @ reshape(k) / sqrt(60); softmax over axis=1 ----------------
__global__ __launch_bounds__(256) void attn_kernel(
    const float* __restrict__ q, const float* __restrict__ kx, float* __restrict__ graph) {
  __shared__ float qb[cKL];
  __shared__ float kb[cKL];
  __shared__ float sc[cK * cK];
  __shared__ float cmax[cK], csum[cK];
  const int b = blockIdx.x;
  const int tid = threadIdx.x;
  for (int idx = tid; idx < cKL; idx += 256) {
    qb[idx] = q[b * cKL + idx];
    kb[idx] = kx[b * cKL + idx];
  }
  __syncthreads();
  const float scale = 1.0f / sqrtf(60.0f);
  for (int idx = tid; idx < cK * cK; idx += 256) {
    int i = idx / cK, j = idx % cK;
    float acc = 0.0f;
    #pragma unroll 4
    for (int t = 0; t < cC; ++t) acc += qb[i * cC + t] * kb[t * cK + j];
    sc[idx] = acc * scale;
  }
  __syncthreads();
  if (tid < cK) {
    float m = -1e30f;
    for (int i = 0; i < cK; ++i) m = fmaxf(m, sc[i * cK + tid]);
    float ssum = 0.0f;
    for (int i = 0; i < cK; ++i) ssum += __expf(sc[i * cK + tid] - m);
    cmax[tid] = m; csum[tid] = ssum;
  }
  __syncthreads();
  for (int idx = tid; idx < cK * cK; idx += 256) {
    int j = idx % cK;
    graph[b * cK * cK + idx] = __expf(sc[idx] - cmax[j]) / csum[j];
  }
}

// ---------------- LSTM: one wave (64 lanes) per sequence, 4 sequences/block ----------------
// Lane j: a0 = gate-row j (i for j<32, f for j>=32); a1 = gate-row j+64 (g / o).
// h broadcast via v_readlane (compile-time lane index -> SGPR operand FMAs, no LDS),
// nonlinearities via v_rcp_f32. Two partial chains halve the 32-FMA dep latency.
__global__ __launch_bounds__(256) void lstm_kernel(
    const float* __restrict__ x, const float* __restrict__ Wih, const float* __restrict__ Whh,
    const float* __restrict__ bih, const float* __restrict__ bhh, float* __restrict__ hout) {
  const int wave = threadIdx.x >> 6;
  const int lane = threadIdx.x & 63;
  const int seq = blockIdx.x * 4 + wave;   // < 6528
  const int j = lane;
  float2 w[32];
  #pragma unroll
  for (int k2 = 0; k2 < 32; ++k2) {
    w[k2].x = Whh[j * 32 + k2];
    w[k2].y = Whh[(j + 64) * 32 + k2];
  }
  const float wix = Wih[j], wiy = Wih[j + 64];
  const float bbx = bih[j] + bhh[j];
  const float bby = bih[j + 64] + bhh[j + 64];
  const float xr = (lane < cL) ? x[seq * cL + lane] : 0.0f;
  float h = 0.0f, c = 0.0f;
  float* outp = hout + (size_t)seq * cL * cH;
  for (int t = 0; t < cL; ++t) {
    const float xt = rdlane(xr, t);
    float ax0 = fmaf(wix, xt, bbx), ay0 = fmaf(wiy, xt, bby);
    float ax1 = 0.0f, ay1 = 0.0f;
    #pragma unroll
    for (int k2 = 0; k2 < 32; k2 += 2) {
      const float hk0 = rdlane(h, k2);
      const float hk1 = rdlane(h, k2 + 1);
      ax0 = fmaf(w[k2].x, hk0, ax0);
      ay0 = fmaf(w[k2].y, hk0, ay0);
      ax1 = fmaf(w[k2 + 1].x, hk1, ax1);
      ay1 = fmaf(w[k2 + 1].y, hk1, ay1);
    }
    const float a0 = ax0 + ax1;
    const float a1 = ay0 + ay1;
    const float sA = fsig(a0);           // lanes<32: sig(i); lanes>=32: sig(f)
    const float sB = fsig(a1);           // lanes>=32: sig(o)
    const float tB = ftanh(a1);          // lanes<32: tanh(g)
    const float p = sA * tB;
    const float sf = __shfl(sA, (lane & 31) + 32);
    const float so = __shfl(sB, (lane & 31) + 32);
    c = fmaf(sf, c, p);
    h = so * ftanh(c);
    if (lane < 32) outp[t * cH + lane] = h;
  }
}

// ---------------- agg: per b, agg = G^T (51x51) @ H (51x1920), 128-col tiles ----------------
__global__ __launch_bounds__(256) void agg_kernel(
    const float* __restrict__ hbuf, const float* __restrict__ graph,
    float* __restrict__ aggout) {
  __shared__ float G[cK * cK];
  __shared__ __align__(16) float Ht[cK][128];
  const int b = blockIdx.y;
  const int c0 = blockIdx.x * 128;
  const int tid = threadIdx.x;
  for (int idx = tid; idx < cK * cK; idx += 256) G[idx] = graph[b * cK * cK + idx];
  for (int idx = tid; idx < cK * 128; idx += 256) {
    int k = idx >> 7, c = idx & 127;
    Ht[k][c] = hbuf[((size_t)b * cK + k) * 1920 + c0 + c];
  }
  __syncthreads();
  const int jg = tid >> 5;
  const int cg = tid & 31;
  const int cc = cg * 4;
  float4 acc[7];
  #pragma unroll
  for (int jj = 0; jj < 7; ++jj) acc[jj] = make_float4(0.f, 0.f, 0.f, 0.f);
  for (int k = 0; k < cK; ++k) {
    const float4 hv = *reinterpret_cast<const float4*>(&Ht[k][cc]);
    #pragma unroll
    for (int jj = 0; jj < 7; ++jj) {
      const int j = jg + jj * 8;
      const float g = (j < cK) ? G[k * cK + j] : 0.0f;
      acc[jj].x += g * hv.x; acc[jj].y += g * hv.y;
      acc[jj].z += g * hv.z; acc[jj].w += g * hv.w;
    }
  }
  #pragma unroll
  for (int jj = 0; jj < 7; ++jj) {
    const int j = jg + jj * 8;
    if (j < cK) {
      const size_t o = ((size_t)b * cK + j) * 1920 + c0 + cc;
      aggout[o + 0] = acc[jj].x; aggout[o + 1] = acc[jj].y;
      aggout[o + 2] = acc[jj].z; aggout[o + 3] = acc[jj].w;
    }
  }
}

// ---------------- gnn2: per-row h_gcn_pre = relu(agg@Wn + bn + hm@Wr) @ W2 + b2 ----------------
__global__ __launch_bounds__(256) void gnn2_kernel(
    const float* __restrict__ hbuf, const float* __restrict__ Wn,
    const float* __restrict__ bn_, const float* __restrict__ Wr,
    const float* __restrict__ W2, const float* __restrict__ b2,
    float* __restrict__ hg) {
  __shared__ __align__(16) float wn[cH * cH];
  __shared__ __align__(16) float wr[cH * cH];
  __shared__ __align__(16) float w2[cH * cH];
  __shared__ float bnb[cH], b2b[cH];
  __shared__ float A_[192][33];
  __shared__ float M_[192][33];
  const int tid = threadIdx.x;
  const int row0 = blockIdx.x * 192;
  for (int idx = tid; idx < cH * cH; idx += 256) { wn[idx] = Wn[idx]; wr[idx] = Wr[idx]; w2[idx] = W2[idx]; }
  if (tid < cH) { bnb[tid] = bn_[tid]; b2b[tid] = b2[tid]; }
  for (int idx = tid; idx < 192 * 32; idx += 256) {
    const int r = idx >> 5, d = idx & 31;
    A_[r][d] = hg[(size_t)(row0 + r) * 32 + d];
    const int g = row0 + r;
    const int l = g % 60;
    M_[r][d] = (l > 0) ? hbuf[(size_t)(g - 1) * 32 + d] : 0.0f;
  }
  __syncthreads();
  const int rg = tid >> 2;
  const int cg = tid & 3;
  const int c0 = cg * 8;
  const int r0 = rg * 3;
  float acc[3][8];
  #pragma unroll
  for (int i = 0; i < 3; ++i)
    #pragma unroll
    for (int d = 0; d < 8; ++d) acc[i][d] = bnb[c0 + d];
  for (int e = 0; e < cH; ++e) {
    const float4 wn0 = *reinterpret_cast<const float4*>(&wn[e * cH + c0]);
    const float4 wn1 = *reinterpret_cast<const float4*>(&wn[e * cH + c0 + 4]);
    const float4 wr0 = *reinterpret_cast<const float4*>(&wr[e * cH + c0]);
    const float4 wr1 = *reinterpret_cast<const float4*>(&wr[e * cH + c0 + 4]);
    #pragma unroll
    for (int i = 0; i < 3; ++i) {
      const float a = A_[r0 + i][e];
      const float m = M_[r0 + i][e];
      acc[i][0] += a * wn0.x + m * wr0.x; acc[i][1] += a * wn0.y + m * wr0.y;
      acc[i][2] += a * wn0.z + m * wr0.z; acc[i][3] += a * wn0.w + m * wr0.w;
      acc[i][4] += a * wn1.x + m * wr1.x; acc[i][5] += a * wn1.y + m * wr1.y;
      acc[i][6] += a * wn1.z + m * wr1.z; acc[i][7] += a * wn1.w + m * wr1.w;
    }
  }
  __syncthreads();
  #pragma unroll
  for (int i = 0; i < 3; ++i)
    #pragma unroll
    for (int d = 0; d < 8; ++d) A_[r0 + i][c0 + d] = fmaxf(acc[i][d], 0.0f);
  __syncthreads();
  float acc2[3][8];
  #pragma unroll
  for (int i = 0; i < 3; ++i)
    #pragma unroll
    for (int d = 0; d < 8; ++d) acc2[i][d] = b2b[c0 + d];
  for (int e = 0; e < cH; ++e) {
    const float4 w20 = *reinterpret_cast<const float4*>(&w2[e * cH + c0]);
    const float4 w21 = *reinterpret_cast<const float4*>(&w2[e * cH + c0 + 4]);
    #pragma unroll
    for (int i = 0; i < 3; ++i) {
      const float t = A_[r0 + i][e];
      acc2[i][0] += t * w20.x; acc2[i][1] += t * w20.y;
      acc2[i][2] += t * w20.z; acc2[i][3] += t * w20.w;
      acc2[i][4] += t * w21.x; acc2[i][5] += t * w21.y;
      acc2[i][6] += t * w21.z; acc2[i][7] += t * w21.w;
    }
  }
  #pragma unroll
  for (int i = 0; i < 3; ++i)
    #pragma unroll
    for (int d = 0; d < 8; ++d) M_[r0 + i][c0 + d] = acc2[i][d];
  __syncthreads();
  for (int idx = tid; idx < 192 * 32; idx += 256) {
    const int r = idx >> 5, d = idx & 31;
    hg[(size_t)row0 * 32 + idx] = M_[r][d];
  }
}

// ---------------- split-K GEMM (fp32, small): partial[s] = A[:, ks:+64] @ W[ks:+64, n0:+64] ----------------
__global__ __launch_bounds__(256) void gemm_splitk_kernel(
    const float* __restrict__ A, const float* __restrict__ W,
    int K, int N, float* __restrict__ partial) {
  __shared__ __align__(16) float At[128][65];
  __shared__ __align__(16) float Wt[64][64];
  const int tid = threadIdx.x;
  const int n0 = blockIdx.x * 64;
  const int k0 = blockIdx.y * 64;
  const int kw = min(64, K - k0);
  for (int idx = tid; idx < 128 * 64; idx += 256) {
    int r = idx >> 6, kk = idx & 63;
    At[r][kk] = (kk < kw) ? A[(size_t)r * K + k0 + kk] : 0.0f;
  }
  for (int idx = tid; idx < 64 * 64; idx += 256) {
    int kk = idx >> 6, cc = idx & 63;
    Wt[kk][cc] = (kk < kw && n0 + cc < N) ? W[(size_t)(k0 + kk) * N + n0 + cc] : 0.0f;
  }
  __syncthreads();
  const int cg = tid & 15, rg = tid >> 4;
  const int c0 = cg * 4, r0 = rg * 8;
  float acc[8][4];
  #pragma unroll
  for (int i = 0; i < 8; ++i)
    #pragma unroll
    for (int jj = 0; jj < 4; ++jj) acc[i][jj] = 0.0f;
  for (int kk = 0; kk < 64; kk += 2) {
    const float4 wv0 = *reinterpret_cast<const float4*>(&Wt[kk][c0]);
    const float4 wv1 = *reinterpret_cast<const float4*>(&Wt[kk + 1][c0]);
    #pragma unroll
    for (int i = 0; i < 8; ++i) {
      const float2 av = *reinterpret_cast<const float2*>(&At[r0 + i][kk]);
      acc[i][0] += av.x * wv0.x + av.y * wv1.x;
      acc[i][1] += av.x * wv0.y + av.y * wv1.y;
      acc[i][2] += av.x * wv0.z + av.y * wv1.z;
      acc[i][3] += av.x * wv0.w + av.y * wv1.w;
    }
  }
  float* p = partial + (size_t)blockIdx.y * 128 * N;
  #pragma unroll
  for (int i = 0; i < 8; ++i) {
    #pragma unroll
    for (int jj = 0; jj < 4; ++jj) {
      const int cc = n0 + c0 + jj;
      if (cc < N) p[(r0 + i) * N + cc] = acc[i][jj];
    }
  }
}

__global__ __launch_bounds__(256) void mlpred_kernel(
    const float* __restrict__ partial, int S, int N,
    const float* __restrict__ bias, const float* __restrict__ gg,
    const float* __restrict__ bb, const float* __restrict__ mm,
    const float* __restrict__ vv, float* __restrict__ outz) {
  const int oi = blockIdx.x * 256 + threadIdx.x;
  if (oi >= 128 * N) return;
  float s = 0.0f;
  for (int p = 0; p < S; ++p) s += partial[(size_t)p * 128 * N + oi];
  const int c = oi % N;
  const float z = fmaxf(s + bias[c], 0.0f);
  outz[oi] = (z - mm[c]) * rsqrtf(vv[c] + 1e-5f) * gg[c] + bb[c];
}

// bn-epilogue for layer 2 that emits bf16 z2 zero-padded to [128][512] (K pad for MFMA)
__global__ __launch_bounds__(256) void mlpredbf_kernel(
    const float* __restrict__ partial, int S,
    const float* __restrict__ bias, const float* __restrict__ gg,
    const float* __restrict__ bb, const float* __restrict__ mm,
    const float* __restrict__ vv, unsigned short* __restrict__ outbf) {
  const int oi = blockIdx.x * 256 + threadIdx.x;   // over 128*512
  if (oi >= 128 * 512) return;
  const int r = oi >> 9, c = oi & 511;
  unsigned short val = 0;
  if (c < 500) {
    float s = 0.0f;
    for (int p = 0; p < S; ++p) s += partial[(size_t)p * 64000 + r * 500 + c];
    const float z = fmaxf(s + bias[c], 0.0f);
    const float y = (z - mm[c]) * rsqrtf(vv[c] + 1e-5f) * gg[c] + bb[c];
    val = (unsigned short)f2bf(y);
  }
  outbf[oi] = val;
}

// ---------------- big GEMM via bf16 MFMA: h_gcn += z2 @ W3 + b3 (RMW) ----------------
// 765 blocks x (128 rows x 128 cols). 4 waves: wave wv owns cols [wv*32, wv*32+32),
// all 128 rows as 4 M-frags. A (z2bf [128][512], L2-hot) read straight to frags.
// B staged fp32->bf16 via v_cvt_pk into reg-double-buffered LDS, ONE barrier/K-step.
// LDS layout Bs[k-pair][n] u32(bf16 lo=k even, hi=k odd): b128 writes bank-uniform,
// frag reads = 4x ds_read_b32 with bank = lane&31 (2-way = free).
// C/D: col=lane&31, row=(reg&3)+8*(reg>>2)+4*(lane>>5)  [m74/m101 verified]
__global__ __launch_bounds__(256, 3) void w3_mfma_kernel(
    const unsigned short* __restrict__ z2bf, const float* __restrict__ W3,
    const float* __restrict__ b3, float* __restrict__ outh) {
  __shared__ unsigned Bs[2][16][128];
  const int tid = threadIdx.x;
  const int n0 = blockIdx.x * 128;
  const int wv = tid >> 6;
  const int lane = tid & 63;
  const int half = lane >> 5;
  const int lm = lane & 31;
  const int kp = tid >> 4;          // 0..15: staged k-pair
  const int nc = (tid & 15) << 3;   // 0..120: staged n-chunk

  accf16 acc[4] = {};

  const unsigned short* Ab = z2bf + lm * 512 + half * 8;
  const float* Wp = W3 + (size_t)(2 * kp) * cKL32 + n0 + nc;

  // prologue: stage k = 0..31 into buf0 (all rows valid)
  {
    const float4 r0a = *reinterpret_cast<const float4*>(Wp);
    const float4 r0b = *reinterpret_cast<const float4*>(Wp + 4);
    const float4 r1a = *reinterpret_cast<const float4*>(Wp + cKL32);
    const float4 r1b = *reinterpret_cast<const float4*>(Wp + cKL32 + 4);
    uint4v w0 = {pk2bf(r0a.x, r1a.x), pk2bf(r0a.y, r1a.y), pk2bf(r0a.z, r1a.z), pk2bf(r0a.w, r1a.w)};
    uint4v w1 = {pk2bf(r0b.x, r1b.x), pk2bf(r0b.y, r1b.y), pk2bf(r0b.z, r1b.z), pk2bf(r0b.w, r1b.w)};
    *reinterpret_cast<uint4v*>(&Bs[0][kp][nc]) = w0;
    *reinterpret_cast<uint4v*>(&Bs[0][kp][nc + 4]) = w1;
  }
  __syncthreads();

  int cur = 0;
  for (int t = 0; t < 16; ++t) {
    const int k0 = t << 5;
    // (1) A fragments first: MFMA then only needs vmcnt(4) (prefetch stays in flight)
    bfrag8 a0[4], a1[4];
    #pragma unroll
    for (int mf = 0; mf < 4; ++mf) {
      a0[mf] = *reinterpret_cast<const bfrag8*>(Ab + mf * 16384 + k0);
      a1[mf] = *reinterpret_cast<const bfrag8*>(Ab + mf * 16384 + k0 + 16);
    }
    // (2) issue next K-tile W3 loads into registers (hide HBM latency under MFMA)
    float4 r0a = make_float4(0.f, 0.f, 0.f, 0.f), r0b = r0a, r1a = r0a, r1b = r0a;
    if (t < 15) {
      const int kA = k0 + 32 + 2 * kp;
      const float* p = Wp + (size_t)(k0 + 32) * cKL32;
      if (kA < 500)     { r0a = *reinterpret_cast<const float4*>(p);
                          r0b = *reinterpret_cast<const float4*>(p + 4); }
      if (kA + 1 < 500) { r1a = *reinterpret_cast<const float4*>(p + cKL32);
                          r1b = *reinterpret_cast<const float4*>(p + cKL32 + 4); }
    }
    // (3) B fragments from LDS
    const unsigned* Bf = &Bs[cur][0][0];
    const int colL = wv * 32 + lm;
    union { unsigned u[4]; bfrag8 b; } cv0, cv1;
    #pragma unroll
    for (int c = 0; c < 4; ++c) cv0.u[c] = Bf[(half * 4 + c) * 128 + colL];
    #pragma unroll
    for (int c = 0; c < 4; ++c) cv1.u[c] = Bf[(8 + half * 4 + c) * 128 + colL];
    // (4) 8 MFMA
    #pragma unroll
    for (int mf = 0; mf < 4; ++mf)
      acc[mf] = __builtin_amdgcn_mfma_f32_32x32x16_bf16(a0[mf], cv0.b, acc[mf], 0, 0, 0);
    #pragma unroll
    for (int mf = 0; mf < 4; ++mf)
      acc[mf] = __builtin_amdgcn_mfma_f32_32x32x16_bf16(a1[mf], cv1.b, acc[mf], 0, 0, 0);
    // (5) pack + write next buffer, single barrier per K-step
    if (t < 15) {
      uint4v w0 = {pk2bf(r0a.x, r1a.x), pk2bf(r0a.y, r1a.y), pk2bf(r0a.z, r1a.z), pk2bf(r0a.w, r1a.w)};
      uint4v w1 = {pk2bf(r0b.x, r1b.x), pk2bf(r0b.y, r1b.y), pk2bf(r0b.z, r1b.z), pk2bf(r0b.w, r1b.w)};
      *reinterpret_cast<uint4v*>(&Bs[cur ^ 1][kp][nc]) = w0;
      *reinterpret_cast<uint4v*>(&Bs[cur ^ 1][kp][nc + 4]) = w1;
    }
    __syncthreads();
    cur ^= 1;
  }

  const int col = n0 + wv * 32 + lm;
  const float bias = b3[col];
  #pragma unroll
  for (int mf = 0; mf < 4; ++mf) {
    #pragma unroll
    for (int reg = 0; reg < 16; ++reg) {
      const int rr = mf * 32 + (reg & 3) + 8 * (reg >> 2) + 4 * half;
      const size_t o = (size_t)rr * cKL32 + col;
      outh[o] += acc[mf][reg] + bias;
    }
  }
}

// ---------------- ann GEMM via bf16 MFMA, split-K x765 ----------------
// partial[bx] = hg[0:128, kb:kb+128] @ annW[kb:kb+128, 0:100]  (kb = bx*128)
// Same structure as w3: 4 waves x 32 cols (cols 100..127 dead), 4 M-frags.
// A (hgcn, L3-hot) loaded direct to frags with on-the-fly cvt_pk.
// B (annW) staged via reg-double-buffered Bs k-pair layout; one barrier/K-step.
__global__ __launch_bounds__(256, 3) void ann_mfma_kernel(
    const float* __restrict__ hg, const float* __restrict__ annW,
    float* __restrict__ partial) {
  __shared__ unsigned Bs[2][16][128];
  const int tid = threadIdx.x;
  const int bx = blockIdx.x;          // 765
  const int kbase = bx * 128;
  const int wv = tid >> 6;
  const int lane = tid & 63;
  const int half = lane >> 5;
  const int lm = lane & 31;

  accf16 acc[4] = {};

  // prologue: stage k-pairs of [kbase, kbase+32) into buf0
  #pragma unroll
  for (int i = 0; i < 8; ++i) {
    const int idx = tid + i * 256;          // 0..2047
    const int kp = idx >> 7, col = idx & 127;
    float w0 = 0.f, w1 = 0.f;
    if (col < 100) {
      const size_t base = (size_t)(kbase + 2 * kp) * 100 + col;
      w0 = annW[base];
      w1 = annW[base + 100];
    }
    Bs[0][kp][col] = pk2bf(w0, w1);
  }
  __syncthreads();

  const float* Ap = hg + (size_t)lm * cKL32 + kbase + half * 8;
  int cur = 0;
  for (int t = 0; t < 4; ++t) {
    const int k0 = t * 32;
    // (1) A fragments: direct global fp32 loads + cvt (L3-resident hgcn)
    bfrag8 a0[4], a1[4];
    #pragma unroll
    for (int mf = 0; mf < 4; ++mf) {
      const float* p = Ap + (size_t)mf * 32 * cKL32 + k0;
      const float4 f0 = *reinterpret_cast<const float4*>(p);
      const float4 f1 = *reinterpret_cast<const float4*>(p + 4);
      const float4 g0 = *reinterpret_cast<const float4*>(p + 16);
      const float4 g1 = *reinterpret_cast<const float4*>(p + 20);
      union { unsigned u[4]; bfrag8 b; } ua, ub;
      ua.u[0] = pk2bf(f0.x, f0.y); ua.u[1] = pk2bf(f0.z, f0.w);
      ua.u[2] = pk2bf(f1.x, f1.y); ua.u[3] = pk2bf(f1.z, f1.w);
      ub.u[0] = pk2bf(g0.x, g0.y); ub.u[1] = pk2bf(g0.z, g0.w);
      ub.u[2] = pk2bf(g1.x, g1.y); ub.u[3] = pk2bf(g1.z, g1.w);
      a0[mf] = ua.b; a1[mf] = ub.b;
    }
    // (2) prefetch next 32-k slab of annW into registers
    float w0r[8], w1r[8];
    if (t < 3) {
      #pragma unroll
      for (int i = 0; i < 8; ++i) {
        const int idx = tid + i * 256;
        const int kp = idx >> 7, col = idx & 127;
        w0r[i] = 0.f; w1r[i] = 0.f;
        if (col < 100) {
          const size_t base = (size_t)(kbase + (t + 1) * 32 + 2 * kp) * 100 + col;
          w0r[i] = annW[base];
          w1r[i] = annW[base + 100];
        }
      }
    }
    // (3) B fragments from LDS
    const unsigned* Bf = &Bs[cur][0][0];
    const int colL = wv * 32 + lm;
    union { unsigned u[4]; bfrag8 b; } cv0, cv1;
    #pragma unroll
    for (int c = 0; c < 4; ++c) cv0.u[c] = Bf[(half * 4 + c) * 128 + colL];
    #pragma unroll
    for (int c = 0; c < 4; ++c) cv1.u[c] = Bf[(8 + half * 4 + c) * 128 + colL];
    // (4) 8 MFMA
    #pragma unroll
    for (int mf = 0; mf < 4; ++mf)
      acc[mf] = __builtin_amdgcn_mfma_f32_32x32x16_bf16(a0[mf], cv0.b, acc[mf], 0, 0, 0);
    #pragma unroll
    for (int mf = 0; mf < 4; ++mf)
      acc[mf] = __builtin_amdgcn_mfma_f32_32x32x16_bf16(a1[mf], cv1.b, acc[mf], 0, 0, 0);
    // (5) pack + write next buffer
    if (t < 3) {
      #pragma unroll
      for (int i = 0; i < 8; ++i) {
        const int idx = tid + i * 256;
        const int kp = idx >> 7, col = idx & 127;
        Bs[cur ^ 1][kp][col] = pk2bf(w0r[i], w1r[i]);
      }
    }
    __syncthreads();
    cur ^= 1;
  }

  const int col = wv * 32 + lm;
  if (col < 100) {
    float* p = partial + (size_t)bx * 12800;
    #pragma unroll
    for (int mf = 0; mf < 4; ++mf) {
      #pragma unroll
      for (int reg = 0; reg < 16; ++reg) {
        const int rr = mf * 32 + (reg & 3) + 8 * (reg >> 2) + 4 * half;
        p[rr * 100 + col] = acc[mf][reg];
      }
    }
  }
}

// stage-1 reduction: partial2[by] = sum of 51 partials (15 groups x 51 = 765)
__global__ __launch_bounds__(256) void annred1_kernel(
    const float* __restrict__ partial, float* __restrict__ partial2) {
  const int oi = blockIdx.x * 256 + threadIdx.x;   // < 12800
  const int by = blockIdx.y;                        // 15
  if (oi >= 12800) return;
  const float* p = partial + (size_t)(by * 51) * 12800 + oi;
  float s = 0.0f;
  #pragma unroll 4
  for (int q = 0; q < 51; ++q) s += p[(size_t)q * 12800];
  partial2[(size_t)by * 12800 + oi] = s;
}

// stage-2: sum 15 groups + bias + relu + BN
__global__ __launch_bounds__(256) void annred2_kernel(
    const float* __restrict__ partial2, const float* __restrict__ ab,
    const float* __restrict__ gg, const float* __restrict__ bb,
    const float* __restrict__ mm, const float* __restrict__ vv, float* __restrict__ hid) {
  const int oi = blockIdx.x * 256 + threadIdx.x;   // < 12800
  if (oi < 12800) {
    float s = 0.0f;
    #pragma unroll
    for (int p = 0; p < 15; ++p) s += partial2[(size_t)p * 12800 + oi];
    const int c = oi % 100;
    const float z = fmaxf(s + ab[c], 0.0f);
    hid[oi] = (z - mm[c]) * rsqrtf(vv[c] + 1e-5f) * gg[c] + bb[c];
  }
}

// ---------------- log_prob: MAF collapses to u = a*x + b (mask_out all zeros) ----------------
__global__ __launch_bounds__(256) void logp_kernel(
    const float* __restrict__ x, const float* __restrict__ mob,
    const float* __restrict__ mlg, const float* __restrict__ mbeta, float* __restrict__ lp) {
  const int b = blockIdx.x;
  const int tid = threadIdx.x;
  const float rs = rsqrtf(1.0f + 1e-5f);
  const float A0 = __expf(mlg[0] - mob[1]) * rs;
  const float B0 = -mob[0] * __expf(-mob[1]) * __expf(mlg[0]) * rs + mbeta[0];
  const float A1 = __expf(mlg[1] - mob[3]) * rs;
  const float B1 = -mob[2] * __expf(-mob[3]) * __expf(mlg[1]) * rs + mbeta[1];
  const float S = (mlg[0] - mob[1]) + (mlg[1] - mob[3]) - logf(1.0f + 1e-5f);
  const float a = A1 * A0;
  const float bc = A1 * B0 + B1;
  float s = 0.0f;
  for (int t = tid; t < cKL; t += 256) {
    const float u = a * x[b * cKL + t] + bc;
    s += u * u;
  }
  #pragma unroll
  for (int off = 32; off > 0; off >>= 1) s += __shfl_down(s, off);
  __shared__ float red[4];
  if ((tid & 63) == 0) red[tid >> 6] = s;
  __syncthreads();
  if (tid == 0) {
    const float tot = red[0] + red[1] + red[2] + red[3];
    lp[b] = -0.5f * tot / (float)cKL + (-0.5f * kLOG2PI + S);
  }
}

__global__ void lpmean_kernel(const float* __restrict__ lp, float* __restrict__ outm) {
  __shared__ float red[128];
  const int tid = threadIdx.x;
  red[tid] = lp[tid];
  __syncthreads();
  for (int off = 64; off > 0; off >>= 1) {
    if (tid < off) red[tid] += red[tid + off];
    __syncthreads();
  }
  if (tid == 0) outm[0] = red[0] / 128.0f;
}

extern "C" void kernel_launch(void* const* d_in, const int* in_sizes, int n_in,
                              void* d_out, int out_size, void* d_ws, size_t ws_size,
                              hipStream_t stream) {
  const float* x    = (const float*)d_in[0];
  const float* Wq   = (const float*)d_in[1];
  const float* bq   = (const float*)d_in[2];
  const float* Wk   = (const float*)d_in[3];
  const float* bk   = (const float*)d_in[4];
  const float* Wih  = (const float*)d_in[5];
  const float* Whh  = (const float*)d_in[6];
  const float* bih  = (const float*)d_in[7];
  const float* bhh  = (const float*)d_in[8];
  const float* gWn  = (const float*)d_in[9];
  const float* gbn  = (const float*)d_in[10];
  const float* gWr  = (const float*)d_in[11];
  const float* gW2  = (const float*)d_in[12];
  const float* gb2  = (const float*)d_in[13];
  const float* W1   = (const float*)d_in[14];
  const float* b1   = (const float*)d_in[15];
  const float* bn1g = (const float*)d_in[16];
  const float* bn1b = (const float*)d_in[17];
  const float* bn1m = (const float*)d_in[18];
  const float* bn1v = (const float*)d_in[19];
  const float* W2m  = (const float*)d_in[20];
  const float* b2m  = (const float*)d_in[21];
  const float* bn2g = (const float*)d_in[22];
  const float* bn2b = (const float*)d_in[23];
  const float* bn2m = (const float*)d_in[24];
  const float* bn2v = (const float*)d_in[25];
  const float* W3   = (const float*)d_in[26];
  const float* b3   = (const float*)d_in[27];
  const float* annW = (const float*)d_in[28];
  const float* annb = (const float*)d_in[29];
  const float* abg  = (const float*)d_in[30];
  const float* abb  = (const float*)d_in[31];
  const float* abm  = (const float*)d_in[32];
  const float* abv  = (const float*)d_in[33];
  const float* mob  = (const float*)d_in[38];
  const float* mlg  = (const float*)d_in[39];
  const float* mbeta= (const float*)d_in[40];

  float* ws = (float*)d_ws;
  float* qb    = ws;                    // 391680
  float* kb    = ws + 391680;           // 391680
  float* graph = ws + 783360;           // 332928
  float* hbuf  = ws + 1116288;          // 12533760
  float* z1    = ws + 13650048;         // 64000
  unsigned short* z2bf = (unsigned short*)(ws + 13714048);  // 128x512 bf16
  float* partial  = hbuf;               // ann split-K partials: 765*12800 = 9.79M floats
  float* partial2 = hbuf + 10000000;    // 15*12800 = 192000 floats
  float* mp    = hbuf + 4000000;        // mlp split-K partials (dead before ann)

  float* outF = (float*)d_out;
  float* hid  = outF;                   // 12800
  float* lpm  = outF + 12800;           // 1
  float* hgcn = outF + 12801;           // 12533760
  float* lp   = outF + 12546561;        // 128

  qk_kernel<<<816, 256, 0, stream>>>(x, Wq, bq, Wk, bk, qb, kb);
  attn_kernel<<<128, 256, 0, stream>>>(qb, kb, graph);
  lstm_kernel<<<1632, 256, 0, stream>>>(x, Wih, Whh, bih, bhh, hbuf);
  agg_kernel<<<dim3(15, 128), 256, 0, stream>>>(hbuf, graph, hgcn);
  gnn2_kernel<<<2040, 256, 0, stream>>>(hbuf, gWn, gbn, gWr, gW2, gb2, hgcn);
  gemm_splitk_kernel<<<dim3(8, 48), 256, 0, stream>>>(x, W1, 3060, 500, mp);
  mlpred_kernel<<<250, 256, 0, stream>>>(mp, 48, 500, b1, bn1g, bn1b, bn1m, bn1v, z1);
  gemm_splitk_kernel<<<dim3(8, 8), 256, 0, stream>>>(z1, W2m, 500, 500, mp);
  mlpredbf_kernel<<<256, 256, 0, stream>>>(mp, 8, b2m, bn2g, bn2b, bn2m, bn2v, z2bf);
  w3_mfma_kernel<<<765, 256, 0, stream>>>(z2bf, W3, b3, hgcn);
  ann_mfma_kernel<<<765, 256, 0, stream>>>(hgcn, annW, partial);
  annred1_kernel<<<dim3(50, 15), 256, 0, stream>>>(partial, partial2);
  annred2_kernel<<<50, 256, 0, stream>>>(partial2, annb, abg, abb, abm, abv, hid);
  logp_kernel<<<128, 256, 0, stream>>>(x, mob, mlg, mbeta, lp);
  lpmean_kernel<<<1, 128, 0, stream>>>(lp, lpm);
}

// Round 4
// 750.783 us; speedup vs baseline: 1.5848x; 1.0391x over previous
//
#include <hip/hip_runtime.h>
#include <math.h>

constexpr int cB = 128;
constexpr int cK = 51;
constexpr int cL = 60;
constexpr int cH = 32;
constexpr int cC = 60;           // L*D
constexpr int cKL = 3060;        // K*L
constexpr int cKL32 = 97920;     // K*L*32
constexpr float kLOG2PI = 1.8378770664093453f;

typedef __attribute__((ext_vector_type(8))) short bfrag8;    // 8 bf16 = 4 VGPRs
typedef __attribute__((ext_vector_type(16))) float accf16;   // MFMA 32x32 accumulator
typedef __attribute__((ext_vector_type(4))) float accf4;     // MFMA 16x16 accumulator
typedef __attribute__((ext_vector_type(4))) unsigned uint4v; // 16B LDS write

__device__ __forceinline__ float frcp(float x) { return __builtin_amdgcn_rcpf(x); }
__device__ __forceinline__ float fsig(float x) { return frcp(1.0f + __expf(-x)); }
__device__ __forceinline__ float ftanh(float x) {
  float e = __expf(2.0f * x);
  return 1.0f - 2.0f * frcp(e + 1.0f);
}
__device__ __forceinline__ short f2bf(float f) {   // RNE fp32 -> bf16
  union { float f; unsigned u; } v; v.f = f;
  unsigned r = v.u + 0x7FFFu + ((v.u >> 16) & 1u);
  return (short)(r >> 16);
}
__device__ __forceinline__ unsigned pk2bf(float lo, float hi) {  // 2xf32 -> packed 2xbf16 (RNE)
  unsigned r;
  asm("v_cvt_pk_bf16_f32 %0, %1, %2" : "=v"(r) : "v"(lo), "v"(hi));
  return r;
}

// ---------------- q/k projections: rows = B*K = 6528, 8 rows/block ----------------
__global__ __launch_bounds__(256) void qk_kernel(
    const float* __restrict__ x, const float* __restrict__ Wq, const float* __restrict__ bq,
    const float* __restrict__ Wk, const float* __restrict__ bk,
    float* __restrict__ q, float* __restrict__ kx) {
  __shared__ float xs[8][cC];
  const int row0 = blockIdx.x * 8;
  const int tid = threadIdx.x;
  for (int idx = tid; idx < 8 * cC; idx += 256) {
    int lr = idx / cC, t = idx % cC;
    xs[lr][t] = x[(row0 + lr) * cC + t];
  }
  __syncthreads();
  for (int idx = tid; idx < 8 * 2 * cC; idx += 256) {
    int col = idx % cC;
    int r2 = idx / cC;
    int m = r2 & 1, lr = r2 >> 1;
    const float* W = m ? Wk : Wq;
    float acc = m ? bk[col] : bq[col];
    #pragma unroll 4
    for (int t = 0; t < cC; ++t) acc += xs[lr][t] * W[t * cC + col];
    float* outp = m ? kx : q;
    outp[(row0 + lr) * cC + col] = acc;
  }
}

// ---------------- score = q @ reshape(k) / sqrt(60); softmax over axis=1 ----------------
__global__ __launch_bounds__(256) void attn_kernel(
    const float* __restrict__ q, const float* __restrict__ kx, float* __restrict__ graph) {
  __shared__ float qb[cKL];
  __shared__ float kb[cKL];
  __shared__ float sc[cK * cK];
  __shared__ float cmax[cK], csum[cK];
  const int b = blockIdx.x;
  const int tid = threadIdx.x;
  for (int idx = tid; idx < cKL; idx += 256) {
    qb[idx] = q[b * cKL + idx];
    kb[idx] = kx[b * cKL + idx];
  }
  __syncthreads();
  const float scale = 1.0f / sqrtf(60.0f);
  for (int idx = tid; idx < cK * cK; idx += 256) {
    int i = idx / cK, j = idx % cK;
    float acc = 0.0f;
    #pragma unroll 4
    for (int t = 0; t < cC; ++t) acc += qb[i * cC + t] * kb[t * cK + j];
    sc[idx] = acc * scale;
  }
  __syncthreads();
  if (tid < cK) {
    float m = -1e30f;
    for (int i = 0; i < cK; ++i) m = fmaxf(m, sc[i * cK + tid]);
    float ssum = 0.0f;
    for (int i = 0; i < cK; ++i) ssum += __expf(sc[i * cK + tid] - m);
    cmax[tid] = m; csum[tid] = ssum;
  }
  __syncthreads();
  for (int idx = tid; idx < cK * cK; idx += 256) {
    int j = idx % cK;
    graph[b * cK * cK + idx] = __expf(sc[idx] - cmax[j]) / csum[j];
  }
}

// ---------------- LSTM via MFMA: one wave = 16 sequences, all 60 steps ----------------
// Per step: z[16 seq][128 gates] = h@Whh^T (8x mfma_f32_16x16x32_bf16, one per
// 16-gate tile) with C-init = bias + x_t*WihCol (fp32). Gates i,f,g,o = tiles
// {0,1},{2,3},{4,5},{6,7}. C/D: col=lane&15 (gate-within-tile), row=(lane>>4)*4+reg
// (seq) [m89]. A: A[m=lane&15][k=(lane>>4)*8+j]; B: B[k=(lane>>4)*8+j][n=lane&15].
// h transposed through padded LDS each step (single wave -> in-order LDS).
// Only h@Whh^T is bf16; c-state, x-path, bias are fp32.
__global__ __launch_bounds__(64) void lstm_mfma_kernel(
    const float* __restrict__ x, const float* __restrict__ Wih, const float* __restrict__ Whh,
    const float* __restrict__ bih, const float* __restrict__ bhh, float* __restrict__ hout) {
  __shared__ float xlds[cL][16];       // [t][seq]
  __shared__ __align__(16) float hlds[16][36];  // [seq][hid], pad 36 keeps b128 aligned
  const int lane = threadIdx.x;        // 0..63
  const int n = lane & 15;
  const int grp = lane >> 4;           // 0..3
  const int seq0 = blockIdx.x * 16;

  // stage x transposed (tiny)
  for (int i = lane; i < 16 * cL; i += 64) {
    const int s = i / cL, t = i % cL;
    xlds[t][s] = x[(size_t)(seq0 + s) * cL + t];
  }
  // zero h0
  for (int i = lane; i < 16 * 36; i += 64) (&hlds[0][0])[i] = 0.0f;

  // preload B fragments: 8 gate-tiles of Whh^T  (B[k][gate] = Whh[gate][k])
  bfrag8 bf[8];
  float bias8[8], wih8[8];
  #pragma unroll
  for (int g = 0; g < 8; ++g) {
    const float* wrow = Whh + (g * 16 + n) * cH + grp * 8;
    const float4 p0 = *reinterpret_cast<const float4*>(wrow);
    const float4 p1 = *reinterpret_cast<const float4*>(wrow + 4);
    union { unsigned u[4]; bfrag8 b; } ub;
    ub.u[0] = pk2bf(p0.x, p0.y); ub.u[1] = pk2bf(p0.z, p0.w);
    ub.u[2] = pk2bf(p1.x, p1.y); ub.u[3] = pk2bf(p1.z, p1.w);
    bf[g] = ub.b;
    bias8[g] = bih[g * 16 + n] + bhh[g * 16 + n];
    wih8[g] = Wih[g * 16 + n];            // D=1
  }
  float cst[8];                           // c-state: [half16][reg]
  #pragma unroll
  for (int i = 0; i < 8; ++i) cst[i] = 0.0f;
  __syncthreads();

  float* outp = hout + (size_t)seq0 * cL * cH;
  for (int t = 0; t < cL; ++t) {
    // A-frag: h[seq=n][k=grp*8 .. +7] from LDS, cvt to bf16
    const float4 h0 = *reinterpret_cast<const float4*>(&hlds[n][grp * 8]);
    const float4 h1 = *reinterpret_cast<const float4*>(&hlds[n][grp * 8 + 4]);
    union { unsigned u[4]; bfrag8 b; } ua;
    ua.u[0] = pk2bf(h0.x, h0.y); ua.u[1] = pk2bf(h0.z, h0.w);
    ua.u[2] = pk2bf(h1.x, h1.y); ua.u[3] = pk2bf(h1.z, h1.w);
    // x_t for my 4 C-rows (seqs grp*4..grp*4+3)
    const float4 xt = *reinterpret_cast<const float4*>(&xlds[t][grp * 4]);
    accf4 acc[8];
    #pragma unroll
    for (int g = 0; g < 8; ++g) {
      accf4 ci;
      ci[0] = fmaf(wih8[g], xt.x, bias8[g]);
      ci[1] = fmaf(wih8[g], xt.y, bias8[g]);
      ci[2] = fmaf(wih8[g], xt.z, bias8[g]);
      ci[3] = fmaf(wih8[g], xt.w, bias8[g]);
      acc[g] = __builtin_amdgcn_mfma_f32_16x16x32_bf16(ua.b, bf[g], ci, 0, 0, 0);
    }
    __syncthreads();   // reads of hlds done before overwrite (paranoia; 1 wave)
    #pragma unroll
    for (int hh = 0; hh < 2; ++hh) {
      #pragma unroll
      for (int r = 0; r < 4; ++r) {
        const float iv = acc[0 + hh][r];
        const float fv = acc[2 + hh][r];
        const float gv = acc[4 + hh][r];
        const float ov = acc[6 + hh][r];
        float cs = cst[hh * 4 + r];
        cs = fmaf(fsig(fv), cs, fsig(iv) * ftanh(gv));
        const float hv = fsig(ov) * ftanh(cs);
        cst[hh * 4 + r] = cs;
        hlds[grp * 4 + r][n + hh * 16] = hv;
        outp[(size_t)(grp * 4 + r) * (cL * cH) + t * cH + n + hh * 16] = hv;
      }
    }
    __syncthreads();   // h writes visible before next step's A-frag reads
  }
}

// ---------------- agg: per b, agg = G^T (51x51) @ H (51x1920), 128-col tiles ----------------
__global__ __launch_bounds__(256) void agg_kernel(
    const float* __restrict__ hbuf, const float* __restrict__ graph,
    float* __restrict__ aggout) {
  __shared__ float G[cK * cK];
  __shared__ __align__(16) float Ht[cK][128];
  const int b = blockIdx.y;
  const int c0 = blockIdx.x * 128;
  const int tid = threadIdx.x;
  for (int idx = tid; idx < cK * cK; idx += 256) G[idx] = graph[b * cK * cK + idx];
  for (int idx = tid; idx < cK * 128; idx += 256) {
    int k = idx >> 7, c = idx & 127;
    Ht[k][c] = hbuf[((size_t)b * cK + k) * 1920 + c0 + c];
  }
  __syncthreads();
  const int jg = tid >> 5;
  const int cg = tid & 31;
  const int cc = cg * 4;
  float4 acc[7];
  #pragma unroll
  for (int jj = 0; jj < 7; ++jj) acc[jj] = make_float4(0.f, 0.f, 0.f, 0.f);
  for (int k = 0; k < cK; ++k) {
    const float4 hv = *reinterpret_cast<const float4*>(&Ht[k][cc]);
    #pragma unroll
    for (int jj = 0; jj < 7; ++jj) {
      const int j = jg + jj * 8;
      const float g = (j < cK) ? G[k * cK + j] : 0.0f;
      acc[jj].x += g * hv.x; acc[jj].y += g * hv.y;
      acc[jj].z += g * hv.z; acc[jj].w += g * hv.w;
    }
  }
  #pragma unroll
  for (int jj = 0; jj < 7; ++jj) {
    const int j = jg + jj * 8;
    if (j < cK) {
      const size_t o = ((size_t)b * cK + j) * 1920 + c0 + cc;
      aggout[o + 0] = acc[jj].x; aggout[o + 1] = acc[jj].y;
      aggout[o + 2] = acc[jj].z; aggout[o + 3] = acc[jj].w;
    }
  }
}

// ---------------- gnn2: per-row h_gcn_pre = relu(agg@Wn + bn + hm@Wr) @ W2 + b2 ----------------
__global__ __launch_bounds__(256) void gnn2_kernel(
    const float* __restrict__ hbuf, const float* __restrict__ Wn,
    const float* __restrict__ bn_, const float* __restrict__ Wr,
    const float* __restrict__ W2, const float* __restrict__ b2,
    float* __restrict__ hg) {
  __shared__ __align__(16) float wn[cH * cH];
  __shared__ __align__(16) float wr[cH * cH];
  __shared__ __align__(16) float w2[cH * cH];
  __shared__ float bnb[cH], b2b[cH];
  __shared__ float A_[192][33];
  __shared__ float M_[192][33];
  const int tid = threadIdx.x;
  const int row0 = blockIdx.x * 192;
  for (int idx = tid; idx < cH * cH; idx += 256) { wn[idx] = Wn[idx]; wr[idx] = Wr[idx]; w2[idx] = W2[idx]; }
  if (tid < cH) { bnb[tid] = bn_[tid]; b2b[tid] = b2[tid]; }
  for (int idx = tid; idx < 192 * 32; idx += 256) {
    const int r = idx >> 5, d = idx & 31;
    A_[r][d] = hg[(size_t)(row0 + r) * 32 + d];
    const int g = row0 + r;
    const int l = g % 60;
    M_[r][d] = (l > 0) ? hbuf[(size_t)(g - 1) * 32 + d] : 0.0f;
  }
  __syncthreads();
  const int rg = tid >> 2;
  const int cg = tid & 3;
  const int c0 = cg * 8;
  const int r0 = rg * 3;
  float acc[3][8];
  #pragma unroll
  for (int i = 0; i < 3; ++i)
    #pragma unroll
    for (int d = 0; d < 8; ++d) acc[i][d] = bnb[c0 + d];
  for (int e = 0; e < cH; ++e) {
    const float4 wn0 = *reinterpret_cast<const float4*>(&wn[e * cH + c0]);
    const float4 wn1 = *reinterpret_cast<const float4*>(&wn[e * cH + c0 + 4]);
    const float4 wr0 = *reinterpret_cast<const float4*>(&wr[e * cH + c0]);
    const float4 wr1 = *reinterpret_cast<const float4*>(&wr[e * cH + c0 + 4]);
    #pragma unroll
    for (int i = 0; i < 3; ++i) {
      const float a = A_[r0 + i][e];
      const float m = M_[r0 + i][e];
      acc[i][0] += a * wn0.x + m * wr0.x; acc[i][1] += a * wn0.y + m * wr0.y;
      acc[i][2] += a * wn0.z + m * wr0.z; acc[i][3] += a * wn0.w + m * wr0.w;
      acc[i][4] += a * wn1.x + m * wr1.x; acc[i][5] += a * wn1.y + m * wr1.y;
      acc[i][6] += a * wn1.z + m * wr1.z; acc[i][7] += a * wn1.w + m * wr1.w;
    }
  }
  __syncthreads();
  #pragma unroll
  for (int i = 0; i < 3; ++i)
    #pragma unroll
    for (int d = 0; d < 8; ++d) A_[r0 + i][c0 + d] = fmaxf(acc[i][d], 0.0f);
  __syncthreads();
  float acc2[3][8];
  #pragma unroll
  for (int i = 0; i < 3; ++i)
    #pragma unroll
    for (int d = 0; d < 8; ++d) acc2[i][d] = b2b[c0 + d];
  for (int e = 0; e < cH; ++e) {
    const float4 w20 = *reinterpret_cast<const float4*>(&w2[e * cH + c0]);
    const float4 w21 = *reinterpret_cast<const float4*>(&w2[e * cH + c0 + 4]);
    #pragma unroll
    for (int i = 0; i < 3; ++i) {
      const float t = A_[r0 + i][e];
      acc2[i][0] += t * w20.x; acc2[i][1] += t * w20.y;
      acc2[i][2] += t * w20.z; acc2[i][3] += t * w20.w;
      acc2[i][4] += t * w21.x; acc2[i][5] += t * w21.y;
      acc2[i][6] += t * w21.z; acc2[i][7] += t * w21.w;
    }
  }
  #pragma unroll
  for (int i = 0; i < 3; ++i)
    #pragma unroll
    for (int d = 0; d < 8; ++d) M_[r0 + i][c0 + d] = acc2[i][d];
  __syncthreads();
  for (int idx = tid; idx < 192 * 32; idx += 256) {
    const int r = idx >> 5, d = idx & 31;
    hg[(size_t)row0 * 32 + idx] = M_[r][d];
  }
}

// ---------------- split-K GEMM (fp32, small): partial[s] = A[:, ks:+64] @ W[ks:+64, n0:+64] ----------------
__global__ __launch_bounds__(256) void gemm_splitk_kernel(
    const float* __restrict__ A, const float* __restrict__ W,
    int K, int N, float* __restrict__ partial) {
  __shared__ __align__(16) float At[128][65];
  __shared__ __align__(16) float Wt[64][64];
  const int tid = threadIdx.x;
  const int n0 = blockIdx.x * 64;
  const int k0 = blockIdx.y * 64;
  const int kw = min(64, K - k0);
  for (int idx = tid; idx < 128 * 64; idx += 256) {
    int r = idx >> 6, kk = idx & 63;
    At[r][kk] = (kk < kw) ? A[(size_t)r * K + k0 + kk] : 0.0f;
  }
  for (int idx = tid; idx < 64 * 64; idx += 256) {
    int kk = idx >> 6, cc = idx & 63;
    Wt[kk][cc] = (kk < kw && n0 + cc < N) ? W[(size_t)(k0 + kk) * N + n0 + cc] : 0.0f;
  }
  __syncthreads();
  const int cg = tid & 15, rg = tid >> 4;
  const int c0 = cg * 4, r0 = rg * 8;
  float acc[8][4];
  #pragma unroll
  for (int i = 0; i < 8; ++i)
    #pragma unroll
    for (int jj = 0; jj < 4; ++jj) acc[i][jj] = 0.0f;
  for (int kk = 0; kk < 64; kk += 2) {
    const float4 wv0 = *reinterpret_cast<const float4*>(&Wt[kk][c0]);
    const float4 wv1 = *reinterpret_cast<const float4*>(&Wt[kk + 1][c0]);
    #pragma unroll
    for (int i = 0; i < 8; ++i) {
      const float2 av = *reinterpret_cast<const float2*>(&At[r0 + i][kk]);
      acc[i][0] += av.x * wv0.x + av.y * wv1.x;
      acc[i][1] += av.x * wv0.y + av.y * wv1.y;
      acc[i][2] += av.x * wv0.z + av.y * wv1.z;
      acc[i][3] += av.x * wv0.w + av.y * wv1.w;
    }
  }
  float* p = partial + (size_t)blockIdx.y * 128 * N;
  #pragma unroll
  for (int i = 0; i < 8; ++i) {
    #pragma unroll
    for (int jj = 0; jj < 4; ++jj) {
      const int cc = n0 + c0 + jj;
      if (cc < N) p[(r0 + i) * N + cc] = acc[i][jj];
    }
  }
}

__global__ __launch_bounds__(256) void mlpred_kernel(
    const float* __restrict__ partial, int S, int N,
    const float* __restrict__ bias, const float* __restrict__ gg,
    const float* __restrict__ bb, const float* __restrict__ mm,
    const float* __restrict__ vv, float* __restrict__ outz) {
  const int oi = blockIdx.x * 256 + threadIdx.x;
  if (oi >= 128 * N) return;
  float s = 0.0f;
  for (int p = 0; p < S; ++p) s += partial[(size_t)p * 128 * N + oi];
  const int c = oi % N;
  const float z = fmaxf(s + bias[c], 0.0f);
  outz[oi] = (z - mm[c]) * rsqrtf(vv[c] + 1e-5f) * gg[c] + bb[c];
}

// bn-epilogue for layer 2 that emits bf16 z2 zero-padded to [128][512] (K pad for MFMA)
__global__ __launch_bounds__(256) void mlpredbf_kernel(
    const float* __restrict__ partial, int S,
    const float* __restrict__ bias, const float* __restrict__ gg,
    const float* __restrict__ bb, const float* __restrict__ mm,
    const float* __restrict__ vv, unsigned short* __restrict__ outbf) {
  const int oi = blockIdx.x * 256 + threadIdx.x;   // over 128*512
  if (oi >= 128 * 512) return;
  const int r = oi >> 9, c = oi & 511;
  unsigned short val = 0;
  if (c < 500) {
    float s = 0.0f;
    for (int p = 0; p < S; ++p) s += partial[(size_t)p * 64000 + r * 500 + c];
    const float z = fmaxf(s + bias[c], 0.0f);
    const float y = (z - mm[c]) * rsqrtf(vv[c] + 1e-5f) * gg[c] + bb[c];
    val = (unsigned short)f2bf(y);
  }
  outbf[oi] = val;
}

// ---------------- big GEMM via bf16 MFMA: h_gcn += z2 @ W3 + b3 (RMW) ----------------
__global__ __launch_bounds__(256, 3) void w3_mfma_kernel(
    const unsigned short* __restrict__ z2bf, const float* __restrict__ W3,
    const float* __restrict__ b3, float* __restrict__ outh) {
  __shared__ unsigned Bs[2][16][128];
  const int tid = threadIdx.x;
  const int n0 = blockIdx.x * 128;
  const int wv = tid >> 6;
  const int lane = tid & 63;
  const int half = lane >> 5;
  const int lm = lane & 31;
  const int kp = tid >> 4;          // 0..15: staged k-pair
  const int nc = (tid & 15) << 3;   // 0..120: staged n-chunk

  accf16 acc[4] = {};

  const unsigned short* Ab = z2bf + lm * 512 + half * 8;
  const float* Wp = W3 + (size_t)(2 * kp) * cKL32 + n0 + nc;

  // prologue: stage k = 0..31 into buf0 (all rows valid)
  {
    const float4 r0a = *reinterpret_cast<const float4*>(Wp);
    const float4 r0b = *reinterpret_cast<const float4*>(Wp + 4);
    const float4 r1a = *reinterpret_cast<const float4*>(Wp + cKL32);
    const float4 r1b = *reinterpret_cast<const float4*>(Wp + cKL32 + 4);
    uint4v w0 = {pk2bf(r0a.x, r1a.x), pk2bf(r0a.y, r1a.y), pk2bf(r0a.z, r1a.z), pk2bf(r0a.w, r1a.w)};
    uint4v w1 = {pk2bf(r0b.x, r1b.x), pk2bf(r0b.y, r1b.y), pk2bf(r0b.z, r1b.z), pk2bf(r0b.w, r1b.w)};
    *reinterpret_cast<uint4v*>(&Bs[0][kp][nc]) = w0;
    *reinterpret_cast<uint4v*>(&Bs[0][kp][nc + 4]) = w1;
  }
  __syncthreads();

  int cur = 0;
  for (int t = 0; t < 16; ++t) {
    const int k0 = t << 5;
    bfrag8 a0[4], a1[4];
    #pragma unroll
    for (int mf = 0; mf < 4; ++mf) {
      a0[mf] = *reinterpret_cast<const bfrag8*>(Ab + mf * 16384 + k0);
      a1[mf] = *reinterpret_cast<const bfrag8*>(Ab + mf * 16384 + k0 + 16);
    }
    float4 r0a = make_float4(0.f, 0.f, 0.f, 0.f), r0b = r0a, r1a = r0a, r1b = r0a;
    if (t < 15) {
      const int kA = k0 + 32 + 2 * kp;
      const float* p = Wp + (size_t)(k0 + 32) * cKL32;
      if (kA < 500)     { r0a = *reinterpret_cast<const float4*>(p);
                          r0b = *reinterpret_cast<const float4*>(p + 4); }
      if (kA + 1 < 500) { r1a = *reinterpret_cast<const float4*>(p + cKL32);
                          r1b = *reinterpret_cast<const float4*>(p + cKL32 + 4); }
    }
    const unsigned* Bf = &Bs[cur][0][0];
    const int colL = wv * 32 + lm;
    union { unsigned u[4]; bfrag8 b; } cv0, cv1;
    #pragma unroll
    for (int c = 0; c < 4; ++c) cv0.u[c] = Bf[(half * 4 + c) * 128 + colL];
    #pragma unroll
    for (int c = 0; c < 4; ++c) cv1.u[c] = Bf[(8 + half * 4 + c) * 128 + colL];
    #pragma unroll
    for (int mf = 0; mf < 4; ++mf)
      acc[mf] = __builtin_amdgcn_mfma_f32_32x32x16_bf16(a0[mf], cv0.b, acc[mf], 0, 0, 0);
    #pragma unroll
    for (int mf = 0; mf < 4; ++mf)
      acc[mf] = __builtin_amdgcn_mfma_f32_32x32x16_bf16(a1[mf], cv1.b, acc[mf], 0, 0, 0);
    if (t < 15) {
      uint4v w0 = {pk2bf(r0a.x, r1a.x), pk2bf(r0a.y, r1a.y), pk2bf(r0a.z, r1a.z), pk2bf(r0a.w, r1a.w)};
      uint4v w1 = {pk2bf(r0b.x, r1b.x), pk2bf(r0b.y, r1b.y), pk2bf(r0b.z, r1b.z), pk2bf(r0b.w, r1b.w)};
      *reinterpret_cast<uint4v*>(&Bs[cur ^ 1][kp][nc]) = w0;
      *reinterpret_cast<uint4v*>(&Bs[cur ^ 1][kp][nc + 4]) = w1;
    }
    __syncthreads();
    cur ^= 1;
  }

  const int col = n0 + wv * 32 + lm;
  const float bias = b3[col];
  #pragma unroll
  for (int mf = 0; mf < 4; ++mf) {
    #pragma unroll
    for (int reg = 0; reg < 16; ++reg) {
      const int rr = mf * 32 + (reg & 3) + 8 * (reg >> 2) + 4 * half;
      const size_t o = (size_t)rr * cKL32 + col;
      outh[o] += acc[mf][reg] + bias;
    }
  }
}

// ---------------- ann GEMM via bf16 MFMA, split-K x765 ----------------
__global__ __launch_bounds__(256, 3) void ann_mfma_kernel(
    const float* __restrict__ hg, const float* __restrict__ annW,
    float* __restrict__ partial) {
  __shared__ unsigned Bs[2][16][128];
  const int tid = threadIdx.x;
  const int bx = blockIdx.x;          // 765
  const int kbase = bx * 128;
  const int wv = tid >> 6;
  const int lane = tid & 63;
  const int half = lane >> 5;
  const int lm = lane & 31;

  accf16 acc[4] = {};

  #pragma unroll
  for (int i = 0; i < 8; ++i) {
    const int idx = tid + i * 256;          // 0..2047
    const int kp = idx >> 7, col = idx & 127;
    float w0 = 0.f, w1 = 0.f;
    if (col < 100) {
      const size_t base = (size_t)(kbase + 2 * kp) * 100 + col;
      w0 = annW[base];
      w1 = annW[base + 100];
    }
    Bs[0][kp][col] = pk2bf(w0, w1);
  }
  __syncthreads();

  const float* Ap = hg + (size_t)lm * cKL32 + kbase + half * 8;
  int cur = 0;
  for (int t = 0; t < 4; ++t) {
    const int k0 = t * 32;
    bfrag8 a0[4], a1[4];
    #pragma unroll
    for (int mf = 0; mf < 4; ++mf) {
      const float* p = Ap + (size_t)mf * 32 * cKL32 + k0;
      const float4 f0 = *reinterpret_cast<const float4*>(p);
      const float4 f1 = *reinterpret_cast<const float4*>(p + 4);
      const float4 g0 = *reinterpret_cast<const float4*>(p + 16);
      const float4 g1 = *reinterpret_cast<const float4*>(p + 20);
      union { unsigned u[4]; bfrag8 b; } ua, ub;
      ua.u[0] = pk2bf(f0.x, f0.y); ua.u[1] = pk2bf(f0.z, f0.w);
      ua.u[2] = pk2bf(f1.x, f1.y); ua.u[3] = pk2bf(f1.z, f1.w);
      ub.u[0] = pk2bf(g0.x, g0.y); ub.u[1] = pk2bf(g0.z, g0.w);
      ub.u[2] = pk2bf(g1.x, g1.y); ub.u[3] = pk2bf(g1.z, g1.w);
      a0[mf] = ua.b; a1[mf] = ub.b;
    }
    float w0r[8], w1r[8];
    if (t < 3) {
      #pragma unroll
      for (int i = 0; i < 8; ++i) {
        const int idx = tid + i * 256;
        const int kp = idx >> 7, col = idx & 127;
        w0r[i] = 0.f; w1r[i] = 0.f;
        if (col < 100) {
          const size_t base = (size_t)(kbase + (t + 1) * 32 + 2 * kp) * 100 + col;
          w0r[i] = annW[base];
          w1r[i] = annW[base + 100];
        }
      }
    }
    const unsigned* Bf = &Bs[cur][0][0];
    const int colL = wv * 32 + lm;
    union { unsigned u[4]; bfrag8 b; } cv0, cv1;
    #pragma unroll
    for (int c = 0; c < 4; ++c) cv0.u[c] = Bf[(half * 4 + c) * 128 + colL];
    #pragma unroll
    for (int c = 0; c < 4; ++c) cv1.u[c] = Bf[(8 + half * 4 + c) * 128 + colL];
    #pragma unroll
    for (int mf = 0; mf < 4; ++mf)
      acc[mf] = __builtin_amdgcn_mfma_f32_32x32x16_bf16(a0[mf], cv0.b, acc[mf], 0, 0, 0);
    #pragma unroll
    for (int mf = 0; mf < 4; ++mf)
      acc[mf] = __builtin_amdgcn_mfma_f32_32x32x16_bf16(a1[mf], cv1.b, acc[mf], 0, 0, 0);
    if (t < 3) {
      #pragma unroll
      for (int i = 0; i < 8; ++i) {
        const int idx = tid + i * 256;
        const int kp = idx >> 7, col = idx & 127;
        Bs[cur ^ 1][kp][col] = pk2bf(w0r[i], w1r[i]);
      }
    }
    __syncthreads();
    cur ^= 1;
  }

  const int col = wv * 32 + lm;
  if (col < 100) {
    float* p = partial + (size_t)bx * 12800;
    #pragma unroll
    for (int mf = 0; mf < 4; ++mf) {
      #pragma unroll
      for (int reg = 0; reg < 16; ++reg) {
        const int rr = mf * 32 + (reg & 3) + 8 * (reg >> 2) + 4 * half;
        p[rr * 100 + col] = acc[mf][reg];
      }
    }
  }
}

// stage-1 reduction: partial2[by] = sum of 51 partials (15 groups x 51 = 765)
__global__ __launch_bounds__(256) void annred1_kernel(
    const float* __restrict__ partial, float* __restrict__ partial2) {
  const int oi = blockIdx.x * 256 + threadIdx.x;   // < 12800
  const int by = blockIdx.y;                        // 15
  if (oi >= 12800) return;
  const float* p = partial + (size_t)(by * 51) * 12800 + oi;
  float s = 0.0f;
  #pragma unroll 4
  for (int q = 0; q < 51; ++q) s += p[(size_t)q * 12800];
  partial2[(size_t)by * 12800 + oi] = s;
}

// stage-2: sum 15 groups + bias + relu + BN
__global__ __launch_bounds__(256) void annred2_kernel(
    const float* __restrict__ partial2, const float* __restrict__ ab,
    const float* __restrict__ gg, const float* __restrict__ bb,
    const float* __restrict__ mm, const float* __restrict__ vv, float* __restrict__ hid) {
  const int oi = blockIdx.x * 256 + threadIdx.x;   // < 12800
  if (oi < 12800) {
    float s = 0.0f;
    #pragma unroll
    for (int p = 0; p < 15; ++p) s += partial2[(size_t)p * 12800 + oi];
    const int c = oi % 100;
    const float z = fmaxf(s + ab[c], 0.0f);
    hid[oi] = (z - mm[c]) * rsqrtf(vv[c] + 1e-5f) * gg[c] + bb[c];
  }
}

// ---------------- log_prob: MAF collapses to u = a*x + b (mask_out all zeros) ----------------
__global__ __launch_bounds__(256) void logp_kernel(
    const float* __restrict__ x, const float* __restrict__ mob,
    const float* __restrict__ mlg, const float* __restrict__ mbeta, float* __restrict__ lp) {
  const int b = blockIdx.x;
  const int tid = threadIdx.x;
  const float rs = rsqrtf(1.0f + 1e-5f);
  const float A0 = __expf(mlg[0] - mob[1]) * rs;
  const float B0 = -mob[0] * __expf(-mob[1]) * __expf(mlg[0]) * rs + mbeta[0];
  const float A1 = __expf(mlg[1] - mob[3]) * rs;
  const float B1 = -mob[2] * __expf(-mob[3]) * __expf(mlg[1]) * rs + mbeta[1];
  const float S = (mlg[0] - mob[1]) + (mlg[1] - mob[3]) - logf(1.0f + 1e-5f);
  const float a = A1 * A0;
  const float bc = A1 * B0 + B1;
  float s = 0.0f;
  for (int t = tid; t < cKL; t += 256) {
    const float u = a * x[b * cKL + t] + bc;
    s += u * u;
  }
  #pragma unroll
  for (int off = 32; off > 0; off >>= 1) s += __shfl_down(s, off);
  __shared__ float red[4];
  if ((tid & 63) == 0) red[tid >> 6] = s;
  __syncthreads();
  if (tid == 0) {
    const float tot = red[0] + red[1] + red[2] + red[3];
    lp[b] = -0.5f * tot / (float)cKL + (-0.5f * kLOG2PI + S);
  }
}

__global__ void lpmean_kernel(const float* __restrict__ lp, float* __restrict__ outm) {
  __shared__ float red[128];
  const int tid = threadIdx.x;
  red[tid] = lp[tid];
  __syncthreads();
  for (int off = 64; off > 0; off >>= 1) {
    if (tid < off) red[tid] += red[tid + off];
    __syncthreads();
  }
  if (tid == 0) outm[0] = red[0] / 128.0f;
}

extern "C" void kernel_launch(void* const* d_in, const int* in_sizes, int n_in,
                              void* d_out, int out_size, void* d_ws, size_t ws_size,
                              hipStream_t stream) {
  const float* x    = (const float*)d_in[0];
  const float* Wq   = (const float*)d_in[1];
  const float* bq   = (const float*)d_in[2];
  const float* Wk   = (const float*)d_in[3];
  const float* bk   = (const float*)d_in[4];
  const float* Wih  = (const float*)d_in[5];
  const float* Whh  = (const float*)d_in[6];
  const float* bih  = (const float*)d_in[7];
  const float* bhh  = (const float*)d_in[8];
  const float* gWn  = (const float*)d_in[9];
  const float* gbn  = (const float*)d_in[10];
  const float* gWr  = (const float*)d_in[11];
  const float* gW2  = (const float*)d_in[12];
  const float* gb2  = (const float*)d_in[13];
  const float* W1   = (const float*)d_in[14];
  const float* b1   = (const float*)d_in[15];
  const float* bn1g = (const float*)d_in[16];
  const float* bn1b = (const float*)d_in[17];
  const float* bn1m = (const float*)d_in[18];
  const float* bn1v = (const float*)d_in[19];
  const float* W2m  = (const float*)d_in[20];
  const float* b2m  = (const float*)d_in[21];
  const float* bn2g = (const float*)d_in[22];
  const float* bn2b = (const float*)d_in[23];
  const float* bn2m = (const float*)d_in[24];
  const float* bn2v = (const float*)d_in[25];
  const float* W3   = (const float*)d_in[26];
  const float* b3   = (const float*)d_in[27];
  const float* annW = (const float*)d_in[28];
  const float* annb = (const float*)d_in[29];
  const float* abg  = (const float*)d_in[30];
  const float* abb  = (const float*)d_in[31];
  const float* abm  = (const float*)d_in[32];
  const float* abv  = (const float*)d_in[33];
  const float* mob  = (const float*)d_in[38];
  const float* mlg  = (const float*)d_in[39];
  const float* mbeta= (const float*)d_in[40];

  float* ws = (float*)d_ws;
  float* qb    = ws;                    // 391680
  float* kb    = ws + 391680;           // 391680
  float* graph = ws + 783360;           // 332928
  float* hbuf  = ws + 1116288;          // 12533760
  float* z1    = ws + 13650048;         // 64000
  unsigned short* z2bf = (unsigned short*)(ws + 13714048);  // 128x512 bf16
  float* partial  = hbuf;               // ann split-K partials: 765*12800 = 9.79M floats
  float* partial2 = hbuf + 10000000;    // 15*12800 = 192000 floats
  float* mp    = hbuf + 4000000;        // mlp split-K partials (dead before ann)

  float* outF = (float*)d_out;
  float* hid  = outF;                   // 12800
  float* lpm  = outF + 12800;           // 1
  float* hgcn = outF + 12801;           // 12533760
  float* lp   = outF + 12546561;        // 128

  qk_kernel<<<816, 256, 0, stream>>>(x, Wq, bq, Wk, bk, qb, kb);
  attn_kernel<<<128, 256, 0, stream>>>(qb, kb, graph);
  lstm_mfma_kernel<<<408, 64, 0, stream>>>(x, Wih, Whh, bih, bhh, hbuf);
  agg_kernel<<<dim3(15, 128), 256, 0, stream>>>(hbuf, graph, hgcn);
  gnn2_kernel<<<2040, 256, 0, stream>>>(hbuf, gWn, gbn, gWr, gW2, gb2, hgcn);
  gemm_splitk_kernel<<<dim3(8, 48), 256, 0, stream>>>(x, W1, 3060, 500, mp);
  mlpred_kernel<<<250, 256, 0, stream>>>(mp, 48, 500, b1, bn1g, bn1b, bn1m, bn1v, z1);
  gemm_splitk_kernel<<<dim3(8, 8), 256, 0, stream>>>(z1, W2m, 500, 500, mp);
  mlpredbf_kernel<<<256, 256, 0, stream>>>(mp, 8, b2m, bn2g, bn2b, bn2m, bn2v, z2bf);
  w3_mfma_kernel<<<765, 256, 0, stream>>>(z2bf, W3, b3, hgcn);
  ann_mfma_kernel<<<765, 256, 0, stream>>>(hgcn, annW, partial);
  annred1_kernel<<<dim3(50, 15), 256, 0, stream>>>(partial, partial2);
  annred2_kernel<<<50, 256, 0, stream>>>(partial2, annb, abg, abb, abm, abv, hid);
  logp_kernel<<<128, 256, 0, stream>>>(x, mob, mlg, mbeta, lp);
  lpmean_kernel<<<1, 128, 0, stream>>>(lp, lpm);
}

// Round 5
// 747.681 us; speedup vs baseline: 1.5913x; 1.0041x over previous
//
#include <hip/hip_runtime.h>
#include <math.h>

constexpr int cB = 128;
constexpr int cK = 51;
constexpr int cL = 60;
constexpr int cH = 32;
constexpr int cC = 60;           // L*D
constexpr int cKL = 3060;        // K*L
constexpr int cKL32 = 97920;     // K*L*32
constexpr float kLOG2PI = 1.8378770664093453f;

typedef __attribute__((ext_vector_type(8))) short bfrag8;    // 8 bf16 = 4 VGPRs
typedef __attribute__((ext_vector_type(16))) float accf16;   // MFMA 32x32 accumulator
typedef __attribute__((ext_vector_type(4))) float accf4;     // MFMA 16x16 accumulator
typedef __attribute__((ext_vector_type(4))) unsigned uint4v; // 16B LDS write

__device__ __forceinline__ float frcp(float x) { return __builtin_amdgcn_rcpf(x); }
__device__ __forceinline__ float fsig(float x) { return frcp(1.0f + __expf(-x)); }
__device__ __forceinline__ float ftanh(float x) {
  float e = __expf(2.0f * x);
  return 1.0f - 2.0f * frcp(e + 1.0f);
}
__device__ __forceinline__ short f2bf(float f) {   // RNE fp32 -> bf16
  union { float f; unsigned u; } v; v.f = f;
  unsigned r = v.u + 0x7FFFu + ((v.u >> 16) & 1u);
  return (short)(r >> 16);
}
__device__ __forceinline__ unsigned pk2bf(float lo, float hi) {  // 2xf32 -> packed 2xbf16 (RNE)
  unsigned r;
  asm("v_cvt_pk_bf16_f32 %0, %1, %2" : "=v"(r) : "v"(lo), "v"(hi));
  return r;
}

// ---------------- q/k projections: rows = B*K = 6528, 8 rows/block ----------------
__global__ __launch_bounds__(256) void qk_kernel(
    const float* __restrict__ x, const float* __restrict__ Wq, const float* __restrict__ bq,
    const float* __restrict__ Wk, const float* __restrict__ bk,
    float* __restrict__ q, float* __restrict__ kx) {
  __shared__ float xs[8][cC];
  const int row0 = blockIdx.x * 8;
  const int tid = threadIdx.x;
  for (int idx = tid; idx < 8 * cC; idx += 256) {
    int lr = idx / cC, t = idx % cC;
    xs[lr][t] = x[(row0 + lr) * cC + t];
  }
  __syncthreads();
  for (int idx = tid; idx < 8 * 2 * cC; idx += 256) {
    int col = idx % cC;
    int r2 = idx / cC;
    int m = r2 & 1, lr = r2 >> 1;
    const float* W = m ? Wk : Wq;
    float acc = m ? bk[col] : bq[col];
    #pragma unroll 4
    for (int t = 0; t < cC; ++t) acc += xs[lr][t] * W[t * cC + col];
    float* outp = m ? kx : q;
    outp[(row0 + lr) * cC + col] = acc;
  }
}

// ---------------- score = q @ reshape(k) / sqrt(60); softmax over axis=1 ----------------
__global__ __launch_bounds__(256) void attn_kernel(
    const float* __restrict__ q, const float* __restrict__ kx, float* __restrict__ graph) {
  __shared__ float qb[cKL];
  __shared__ float kb[cKL];
  __shared__ float sc[cK * cK];
  __shared__ float cmax[cK], csum[cK];
  const int b = blockIdx.x;
  const int tid = threadIdx.x;
  for (int idx = tid; idx < cKL; idx += 256) {
    qb[idx] = q[b * cKL + idx];
    kb[idx] = kx[b * cKL + idx];
  }
  __syncthreads();
  const float scale = 1.0f / sqrtf(60.0f);
  for (int idx = tid; idx < cK * cK; idx += 256) {
    int i = idx / cK, j = idx % cK;
    float acc = 0.0f;
    #pragma unroll 4
    for (int t = 0; t < cC; ++t) acc += qb[i * cC + t] * kb[t * cK + j];
    sc[idx] = acc * scale;
  }
  __syncthreads();
  if (tid < cK) {
    float m = -1e30f;
    for (int i = 0; i < cK; ++i) m = fmaxf(m, sc[i * cK + tid]);
    float ssum = 0.0f;
    for (int i = 0; i < cK; ++i) ssum += __expf(sc[i * cK + tid] - m);
    cmax[tid] = m; csum[tid] = ssum;
  }
  __syncthreads();
  for (int idx = tid; idx < cK * cK; idx += 256) {
    int j = idx % cK;
    graph[b * cK * cK + idx] = __expf(sc[idx] - cmax[j]) / csum[j];
  }
}

// ---------------- LSTM via MFMA: one wave = 16 sequences, all 60 steps ----------------
// Per step: z[16 seq][128 gates] = h@Whh^T (8x mfma_f32_16x16x32_bf16) with
// C-init = bias + x_t*WihCol (fp32). Single-wave block: LDS ops execute in
// program order within a wave, so NO per-step barrier is needed — this keeps
// the per-step global h-stores from being drained by the __syncthreads vmcnt(0)
// (which was ~2x500cyc/step). sched_barrier(0) pins compiler ordering of the
// hlds read->write->read sequence at zero runtime cost.
__global__ __launch_bounds__(64) void lstm_mfma_kernel(
    const float* __restrict__ x, const float* __restrict__ Wih, const float* __restrict__ Whh,
    const float* __restrict__ bih, const float* __restrict__ bhh, float* __restrict__ hout) {
  __shared__ float xlds[cL][16];       // [t][seq]
  __shared__ __align__(16) float hlds[16][36];  // [seq][hid], pad 36 keeps b128 aligned
  const int lane = threadIdx.x;        // 0..63
  const int n = lane & 15;
  const int grp = lane >> 4;           // 0..3
  const int seq0 = blockIdx.x * 16;

  // stage x transposed (tiny)
  for (int i = lane; i < 16 * cL; i += 64) {
    const int s = i / cL, t = i % cL;
    xlds[t][s] = x[(size_t)(seq0 + s) * cL + t];
  }
  // zero h0
  for (int i = lane; i < 16 * 36; i += 64) (&hlds[0][0])[i] = 0.0f;

  // preload B fragments: 8 gate-tiles of Whh^T  (B[k][gate] = Whh[gate][k])
  bfrag8 bf[8];
  float bias8[8], wih8[8];
  #pragma unroll
  for (int g = 0; g < 8; ++g) {
    const float* wrow = Whh + (g * 16 + n) * cH + grp * 8;
    const float4 p0 = *reinterpret_cast<const float4*>(wrow);
    const float4 p1 = *reinterpret_cast<const float4*>(wrow + 4);
    union { unsigned u[4]; bfrag8 b; } ub;
    ub.u[0] = pk2bf(p0.x, p0.y); ub.u[1] = pk2bf(p0.z, p0.w);
    ub.u[2] = pk2bf(p1.x, p1.y); ub.u[3] = pk2bf(p1.z, p1.w);
    bf[g] = ub.b;
    bias8[g] = bih[g * 16 + n] + bhh[g * 16 + n];
    wih8[g] = Wih[g * 16 + n];            // D=1
  }
  float cst[8];                           // c-state: [half16][reg]
  #pragma unroll
  for (int i = 0; i < 8; ++i) cst[i] = 0.0f;
  __syncthreads();   // init visible (once; outside the step loop)

  float* outp = hout + (size_t)seq0 * cL * cH;
  for (int t = 0; t < cL; ++t) {
    // A-frag: h[seq=n][k=grp*8 .. +7] from LDS, cvt to bf16
    const float4 h0 = *reinterpret_cast<const float4*>(&hlds[n][grp * 8]);
    const float4 h1 = *reinterpret_cast<const float4*>(&hlds[n][grp * 8 + 4]);
    union { unsigned u[4]; bfrag8 b; } ua;
    ua.u[0] = pk2bf(h0.x, h0.y); ua.u[1] = pk2bf(h0.z, h0.w);
    ua.u[2] = pk2bf(h1.x, h1.y); ua.u[3] = pk2bf(h1.z, h1.w);
    // x_t for my 4 C-rows (seqs grp*4..grp*4+3)
    const float4 xt = *reinterpret_cast<const float4*>(&xlds[t][grp * 4]);
    accf4 acc[8];
    #pragma unroll
    for (int g = 0; g < 8; ++g) {
      accf4 ci;
      ci[0] = fmaf(wih8[g], xt.x, bias8[g]);
      ci[1] = fmaf(wih8[g], xt.y, bias8[g]);
      ci[2] = fmaf(wih8[g], xt.z, bias8[g]);
      ci[3] = fmaf(wih8[g], xt.w, bias8[g]);
      acc[g] = __builtin_amdgcn_mfma_f32_16x16x32_bf16(ua.b, bf[g], ci, 0, 0, 0);
    }
    // pin: hlds reads (above) stay before hlds writes (below)
    __builtin_amdgcn_sched_barrier(0);
    #pragma unroll
    for (int hh = 0; hh < 2; ++hh) {
      #pragma unroll
      for (int r = 0; r < 4; ++r) {
        const float iv = acc[0 + hh][r];
        const float fv = acc[2 + hh][r];
        const float gv = acc[4 + hh][r];
        const float ov = acc[6 + hh][r];
        float cs = cst[hh * 4 + r];
        cs = fmaf(fsig(fv), cs, fsig(iv) * ftanh(gv));
        const float hv = fsig(ov) * ftanh(cs);
        cst[hh * 4 + r] = cs;
        hlds[grp * 4 + r][n + hh * 16] = hv;
        outp[(size_t)(grp * 4 + r) * (cL * cH) + t * cH + n + hh * 16] = hv;
      }
    }
    // pin: this step's hlds writes stay before next step's hlds reads
    __builtin_amdgcn_sched_barrier(0);
  }
}

// ---------------- agg: per b, agg = G^T (51x51) @ H (51x1920), 128-col tiles ----------------
__global__ __launch_bounds__(256) void agg_kernel(
    const float* __restrict__ hbuf, const float* __restrict__ graph,
    float* __restrict__ aggout) {
  __shared__ float G[cK * cK];
  __shared__ __align__(16) float Ht[cK][128];
  const int b = blockIdx.y;
  const int c0 = blockIdx.x * 128;
  const int tid = threadIdx.x;
  for (int idx = tid; idx < cK * cK; idx += 256) G[idx] = graph[b * cK * cK + idx];
  for (int idx = tid; idx < cK * 128; idx += 256) {
    int k = idx >> 7, c = idx & 127;
    Ht[k][c] = hbuf[((size_t)b * cK + k) * 1920 + c0 + c];
  }
  __syncthreads();
  const int jg = tid >> 5;
  const int cg = tid & 31;
  const int cc = cg * 4;
  float4 acc[7];
  #pragma unroll
  for (int jj = 0; jj < 7; ++jj) acc[jj] = make_float4(0.f, 0.f, 0.f, 0.f);
  for (int k = 0; k < cK; ++k) {
    const float4 hv = *reinterpret_cast<const float4*>(&Ht[k][cc]);
    #pragma unroll
    for (int jj = 0; jj < 7; ++jj) {
      const int j = jg + jj * 8;
      const float g = (j < cK) ? G[k * cK + j] : 0.0f;
      acc[jj].x += g * hv.x; acc[jj].y += g * hv.y;
      acc[jj].z += g * hv.z; acc[jj].w += g * hv.w;
    }
  }
  #pragma unroll
  for (int jj = 0; jj < 7; ++jj) {
    const int j = jg + jj * 8;
    if (j < cK) {
      const size_t o = ((size_t)b * cK + j) * 1920 + c0 + cc;
      aggout[o + 0] = acc[jj].x; aggout[o + 1] = acc[jj].y;
      aggout[o + 2] = acc[jj].z; aggout[o + 3] = acc[jj].w;
    }
  }
}

// ---------------- gnn2: per-row h_gcn_pre = relu(agg@Wn + bn + hm@Wr) @ W2 + b2 ----------------
__global__ __launch_bounds__(256) void gnn2_kernel(
    const float* __restrict__ hbuf, const float* __restrict__ Wn,
    const float* __restrict__ bn_, const float* __restrict__ Wr,
    const float* __restrict__ W2, const float* __restrict__ b2,
    float* __restrict__ hg) {
  __shared__ __align__(16) float wn[cH * cH];
  __shared__ __align__(16) float wr[cH * cH];
  __shared__ __align__(16) float w2[cH * cH];
  __shared__ float bnb[cH], b2b[cH];
  __shared__ float A_[192][33];
  __shared__ float M_[192][33];
  const int tid = threadIdx.x;
  const int row0 = blockIdx.x * 192;
  for (int idx = tid; idx < cH * cH; idx += 256) { wn[idx] = Wn[idx]; wr[idx] = Wr[idx]; w2[idx] = W2[idx]; }
  if (tid < cH) { bnb[tid] = bn_[tid]; b2b[tid] = b2[tid]; }
  for (int idx = tid; idx < 192 * 32; idx += 256) {
    const int r = idx >> 5, d = idx & 31;
    A_[r][d] = hg[(size_t)(row0 + r) * 32 + d];
    const int g = row0 + r;
    const int l = g % 60;
    M_[r][d] = (l > 0) ? hbuf[(size_t)(g - 1) * 32 + d] : 0.0f;
  }
  __syncthreads();
  const int rg = tid >> 2;
  const int cg = tid & 3;
  const int c0 = cg * 8;
  const int r0 = rg * 3;
  float acc[3][8];
  #pragma unroll
  for (int i = 0; i < 3; ++i)
    #pragma unroll
    for (int d = 0; d < 8; ++d) acc[i][d] = bnb[c0 + d];
  for (int e = 0; e < cH; ++e) {
    const float4 wn0 = *reinterpret_cast<const float4*>(&wn[e * cH + c0]);
    const float4 wn1 = *reinterpret_cast<const float4*>(&wn[e * cH + c0 + 4]);
    const float4 wr0 = *reinterpret_cast<const float4*>(&wr[e * cH + c0]);
    const float4 wr1 = *reinterpret_cast<const float4*>(&wr[e * cH + c0 + 4]);
    #pragma unroll
    for (int i = 0; i < 3; ++i) {
      const float a = A_[r0 + i][e];
      const float m = M_[r0 + i][e];
      acc[i][0] += a * wn0.x + m * wr0.x; acc[i][1] += a * wn0.y + m * wr0.y;
      acc[i][2] += a * wn0.z + m * wr0.z; acc[i][3] += a * wn0.w + m * wr0.w;
      acc[i][4] += a * wn1.x + m * wr1.x; acc[i][5] += a * wn1.y + m * wr1.y;
      acc[i][6] += a * wn1.z + m * wr1.z; acc[i][7] += a * wn1.w + m * wr1.w;
    }
  }
  __syncthreads();
  #pragma unroll
  for (int i = 0; i < 3; ++i)
    #pragma unroll
    for (int d = 0; d < 8; ++d) A_[r0 + i][c0 + d] = fmaxf(acc[i][d], 0.0f);
  __syncthreads();
  float acc2[3][8];
  #pragma unroll
  for (int i = 0; i < 3; ++i)
    #pragma unroll
    for (int d = 0; d < 8; ++d) acc2[i][d] = b2b[c0 + d];
  for (int e = 0; e < cH; ++e) {
    const float4 w20 = *reinterpret_cast<const float4*>(&w2[e * cH + c0]);
    const float4 w21 = *reinterpret_cast<const float4*>(&w2[e * cH + c0 + 4]);
    #pragma unroll
    for (int i = 0; i < 3; ++i) {
      const float t = A_[r0 + i][e];
      acc2[i][0] += t * w20.x; acc2[i][1] += t * w20.y;
      acc2[i][2] += t * w20.z; acc2[i][3] += t * w20.w;
      acc2[i][4] += t * w21.x; acc2[i][5] += t * w21.y;
      acc2[i][6] += t * w21.z; acc2[i][7] += t * w21.w;
    }
  }
  #pragma unroll
  for (int i = 0; i < 3; ++i)
    #pragma unroll
    for (int d = 0; d < 8; ++d) M_[r0 + i][c0 + d] = acc2[i][d];
  __syncthreads();
  for (int idx = tid; idx < 192 * 32; idx += 256) {
    const int r = idx >> 5, d = idx & 31;
    hg[(size_t)row0 * 32 + idx] = M_[r][d];
  }
}

// ---------------- split-K GEMM (fp32, small): partial[s] = A[:, ks:+64] @ W[ks:+64, n0:+64] ----------------
__global__ __launch_bounds__(256) void gemm_splitk_kernel(
    const float* __restrict__ A, const float* __restrict__ W,
    int K, int N, float* __restrict__ partial) {
  __shared__ __align__(16) float At[128][65];
  __shared__ __align__(16) float Wt[64][64];
  const int tid = threadIdx.x;
  const int n0 = blockIdx.x * 64;
  const int k0 = blockIdx.y * 64;
  const int kw = min(64, K - k0);
  for (int idx = tid; idx < 128 * 64; idx += 256) {
    int r = idx >> 6, kk = idx & 63;
    At[r][kk] = (kk < kw) ? A[(size_t)r * K + k0 + kk] : 0.0f;
  }
  for (int idx = tid; idx < 64 * 64; idx += 256) {
    int kk = idx >> 6, cc = idx & 63;
    Wt[kk][cc] = (kk < kw && n0 + cc < N) ? W[(size_t)(k0 + kk) * N + n0 + cc] : 0.0f;
  }
  __syncthreads();
  const int cg = tid & 15, rg = tid >> 4;
  const int c0 = cg * 4, r0 = rg * 8;
  float acc[8][4];
  #pragma unroll
  for (int i = 0; i < 8; ++i)
    #pragma unroll
    for (int jj = 0; jj < 4; ++jj) acc[i][jj] = 0.0f;
  for (int kk = 0; kk < 64; kk += 2) {
    const float4 wv0 = *reinterpret_cast<const float4*>(&Wt[kk][c0]);
    const float4 wv1 = *reinterpret_cast<const float4*>(&Wt[kk + 1][c0]);
    #pragma unroll
    for (int i = 0; i < 8; ++i) {
      const float2 av = *reinterpret_cast<const float2*>(&At[r0 + i][kk]);
      acc[i][0] += av.x * wv0.x + av.y * wv1.x;
      acc[i][1] += av.x * wv0.y + av.y * wv1.y;
      acc[i][2] += av.x * wv0.z + av.y * wv1.z;
      acc[i][3] += av.x * wv0.w + av.y * wv1.w;
    }
  }
  float* p = partial + (size_t)blockIdx.y * 128 * N;
  #pragma unroll
  for (int i = 0; i < 8; ++i) {
    #pragma unroll
    for (int jj = 0; jj < 4; ++jj) {
      const int cc = n0 + c0 + jj;
      if (cc < N) p[(r0 + i) * N + cc] = acc[i][jj];
    }
  }
}

__global__ __launch_bounds__(256) void mlpred_kernel(
    const float* __restrict__ partial, int S, int N,
    const float* __restrict__ bias, const float* __restrict__ gg,
    const float* __restrict__ bb, const float* __restrict__ mm,
    const float* __restrict__ vv, float* __restrict__ outz) {
  const int oi = blockIdx.x * 256 + threadIdx.x;
  if (oi >= 128 * N) return;
  float s = 0.0f;
  for (int p = 0; p < S; ++p) s += partial[(size_t)p * 128 * N + oi];
  const int c = oi % N;
  const float z = fmaxf(s + bias[c], 0.0f);
  outz[oi] = (z - mm[c]) * rsqrtf(vv[c] + 1e-5f) * gg[c] + bb[c];
}

// bn-epilogue for layer 2 that emits bf16 z2 zero-padded to [128][512] (K pad for MFMA)
__global__ __launch_bounds__(256) void mlpredbf_kernel(
    const float* __restrict__ partial, int S,
    const float* __restrict__ bias, const float* __restrict__ gg,
    const float* __restrict__ bb, const float* __restrict__ mm,
    const float* __restrict__ vv, unsigned short* __restrict__ outbf) {
  const int oi = blockIdx.x * 256 + threadIdx.x;   // over 128*512
  if (oi >= 128 * 512) return;
  const int r = oi >> 9, c = oi & 511;
  unsigned short val = 0;
  if (c < 500) {
    float s = 0.0f;
    for (int p = 0; p < S; ++p) s += partial[(size_t)p * 64000 + r * 500 + c];
    const float z = fmaxf(s + bias[c], 0.0f);
    const float y = (z - mm[c]) * rsqrtf(vv[c] + 1e-5f) * gg[c] + bb[c];
    val = (unsigned short)f2bf(y);
  }
  outbf[oi] = val;
}

// ---------------- big GEMM via bf16 MFMA: h_gcn += z2 @ W3 + b3 (RMW) ----------------
__global__ __launch_bounds__(256, 3) void w3_mfma_kernel(
    const unsigned short* __restrict__ z2bf, const float* __restrict__ W3,
    const float* __restrict__ b3, float* __restrict__ outh) {
  __shared__ unsigned Bs[2][16][128];
  const int tid = threadIdx.x;
  const int n0 = blockIdx.x * 128;
  const int wv = tid >> 6;
  const int lane = tid & 63;
  const int half = lane >> 5;
  const int lm = lane & 31;
  const int kp = tid >> 4;          // 0..15: staged k-pair
  const int nc = (tid & 15) << 3;   // 0..120: staged n-chunk

  accf16 acc[4] = {};

  const unsigned short* Ab = z2bf + lm * 512 + half * 8;
  const float* Wp = W3 + (size_t)(2 * kp) * cKL32 + n0 + nc;

  // prologue: stage k = 0..31 into buf0 (all rows valid)
  {
    const float4 r0a = *reinterpret_cast<const float4*>(Wp);
    const float4 r0b = *reinterpret_cast<const float4*>(Wp + 4);
    const float4 r1a = *reinterpret_cast<const float4*>(Wp + cKL32);
    const float4 r1b = *reinterpret_cast<const float4*>(Wp + cKL32 + 4);
    uint4v w0 = {pk2bf(r0a.x, r1a.x), pk2bf(r0a.y, r1a.y), pk2bf(r0a.z, r1a.z), pk2bf(r0a.w, r1a.w)};
    uint4v w1 = {pk2bf(r0b.x, r1b.x), pk2bf(r0b.y, r1b.y), pk2bf(r0b.z, r1b.z), pk2bf(r0b.w, r1b.w)};
    *reinterpret_cast<uint4v*>(&Bs[0][kp][nc]) = w0;
    *reinterpret_cast<uint4v*>(&Bs[0][kp][nc + 4]) = w1;
  }
  __syncthreads();

  int cur = 0;
  for (int t = 0; t < 16; ++t) {
    const int k0 = t << 5;
    bfrag8 a0[4], a1[4];
    #pragma unroll
    for (int mf = 0; mf < 4; ++mf) {
      a0[mf] = *reinterpret_cast<const bfrag8*>(Ab + mf * 16384 + k0);
      a1[mf] = *reinterpret_cast<const bfrag8*>(Ab + mf * 16384 + k0 + 16);
    }
    float4 r0a = make_float4(0.f, 0.f, 0.f, 0.f), r0b = r0a, r1a = r0a, r1b = r0a;
    if (t < 15) {
      const int kA = k0 + 32 + 2 * kp;
      const float* p = Wp + (size_t)(k0 + 32) * cKL32;
      if (kA < 500)     { r0a = *reinterpret_cast<const float4*>(p);
                          r0b = *reinterpret_cast<const float4*>(p + 4); }
      if (kA + 1 < 500) { r1a = *reinterpret_cast<const float4*>(p + cKL32);
                          r1b = *reinterpret_cast<const float4*>(p + cKL32 + 4); }
    }
    const unsigned* Bf = &Bs[cur][0][0];
    const int colL = wv * 32 + lm;
    union { unsigned u[4]; bfrag8 b; } cv0, cv1;
    #pragma unroll
    for (int c = 0; c < 4; ++c) cv0.u[c] = Bf[(half * 4 + c) * 128 + colL];
    #pragma unroll
    for (int c = 0; c < 4; ++c) cv1.u[c] = Bf[(8 + half * 4 + c) * 128 + colL];
    #pragma unroll
    for (int mf = 0; mf < 4; ++mf)
      acc[mf] = __builtin_amdgcn_mfma_f32_32x32x16_bf16(a0[mf], cv0.b, acc[mf], 0, 0, 0);
    #pragma unroll
    for (int mf = 0; mf < 4; ++mf)
      acc[mf] = __builtin_amdgcn_mfma_f32_32x32x16_bf16(a1[mf], cv1.b, acc[mf], 0, 0, 0);
    if (t < 15) {
      uint4v w0 = {pk2bf(r0a.x, r1a.x), pk2bf(r0a.y, r1a.y), pk2bf(r0a.z, r1a.z), pk2bf(r0a.w, r1a.w)};
      uint4v w1 = {pk2bf(r0b.x, r1b.x), pk2bf(r0b.y, r1b.y), pk2bf(r0b.z, r1b.z), pk2bf(r0b.w, r1b.w)};
      *reinterpret_cast<uint4v*>(&Bs[cur ^ 1][kp][nc]) = w0;
      *reinterpret_cast<uint4v*>(&Bs[cur ^ 1][kp][nc + 4]) = w1;
    }
    __syncthreads();
    cur ^= 1;
  }

  const int col = n0 + wv * 32 + lm;
  const float bias = b3[col];
  #pragma unroll
  for (int mf = 0; mf < 4; ++mf) {
    #pragma unroll
    for (int reg = 0; reg < 16; ++reg) {
      const int rr = mf * 32 + (reg & 3) + 8 * (reg >> 2) + 4 * half;
      const size_t o = (size_t)rr * cKL32 + col;
      outh[o] += acc[mf][reg] + bias;
    }
  }
}

// ---------------- ann GEMM via bf16 MFMA, split-K x765 ----------------
__global__ __launch_bounds__(256, 3) void ann_mfma_kernel(
    const float* __restrict__ hg, const float* __restrict__ annW,
    float* __restrict__ partial) {
  __shared__ unsigned Bs[2][16][128];
  const int tid = threadIdx.x;
  const int bx = blockIdx.x;          // 765
  const int kbase = bx * 128;
  const int wv = tid >> 6;
  const int lane = tid & 63;
  const int half = lane >> 5;
  const int lm = lane & 31;

  accf16 acc[4] = {};

  #pragma unroll
  for (int i = 0; i < 8; ++i) {
    const int idx = tid + i * 256;          // 0..2047
    const int kp = idx >> 7, col = idx & 127;
    float w0 = 0.f, w1 = 0.f;
    if (col < 100) {
      const size_t base = (size_t)(kbase + 2 * kp) * 100 + col;
      w0 = annW[base];
      w1 = annW[base + 100];
    }
    Bs[0][kp][col] = pk2bf(w0, w1);
  }
  __syncthreads();

  const float* Ap = hg + (size_t)lm * cKL32 + kbase + half * 8;
  int cur = 0;
  for (int t = 0; t < 4; ++t) {
    const int k0 = t * 32;
    bfrag8 a0[4], a1[4];
    #pragma unroll
    for (int mf = 0; mf < 4; ++mf) {
      const float* p = Ap + (size_t)mf * 32 * cKL32 + k0;
      const float4 f0 = *reinterpret_cast<const float4*>(p);
      const float4 f1 = *reinterpret_cast<const float4*>(p + 4);
      const float4 g0 = *reinterpret_cast<const float4*>(p + 16);
      const float4 g1 = *reinterpret_cast<const float4*>(p + 20);
      union { unsigned u[4]; bfrag8 b; } ua, ub;
      ua.u[0] = pk2bf(f0.x, f0.y); ua.u[1] = pk2bf(f0.z, f0.w);
      ua.u[2] = pk2bf(f1.x, f1.y); ua.u[3] = pk2bf(f1.z, f1.w);
      ub.u[0] = pk2bf(g0.x, g0.y); ub.u[1] = pk2bf(g0.z, g0.w);
      ub.u[2] = pk2bf(g1.x, g1.y); ub.u[3] = pk2bf(g1.z, g1.w);
      a0[mf] = ua.b; a1[mf] = ub.b;
    }
    float w0r[8], w1r[8];
    if (t < 3) {
      #pragma unroll
      for (int i = 0; i < 8; ++i) {
        const int idx = tid + i * 256;
        const int kp = idx >> 7, col = idx & 127;
        w0r[i] = 0.f; w1r[i] = 0.f;
        if (col < 100) {
          const size_t base = (size_t)(kbase + (t + 1) * 32 + 2 * kp) * 100 + col;
          w0r[i] = annW[base];
          w1r[i] = annW[base + 100];
        }
      }
    }
    const unsigned* Bf = &Bs[cur][0][0];
    const int colL = wv * 32 + lm;
    union { unsigned u[4]; bfrag8 b; } cv0, cv1;
    #pragma unroll
    for (int c = 0; c < 4; ++c) cv0.u[c] = Bf[(half * 4 + c) * 128 + colL];
    #pragma unroll
    for (int c = 0; c < 4; ++c) cv1.u[c] = Bf[(8 + half * 4 + c) * 128 + colL];
    #pragma unroll
    for (int mf = 0; mf < 4; ++mf)
      acc[mf] = __builtin_amdgcn_mfma_f32_32x32x16_bf16(a0[mf], cv0.b, acc[mf], 0, 0, 0);
    #pragma unroll
    for (int mf = 0; mf < 4; ++mf)
      acc[mf] = __builtin_amdgcn_mfma_f32_32x32x16_bf16(a1[mf], cv1.b, acc[mf], 0, 0, 0);
    if (t < 3) {
      #pragma unroll
      for (int i = 0; i < 8; ++i) {
        const int idx = tid + i * 256;
        const int kp = idx >> 7, col = idx & 127;
        Bs[cur ^ 1][kp][col] = pk2bf(w0r[i], w1r[i]);
      }
    }
    __syncthreads();
    cur ^= 1;
  }

  const int col = wv * 32 + lm;
  if (col < 100) {
    float* p = partial + (size_t)bx * 12800;
    #pragma unroll
    for (int mf = 0; mf < 4; ++mf) {
      #pragma unroll
      for (int reg = 0; reg < 16; ++reg) {
        const int rr = mf * 32 + (reg & 3) + 8 * (reg >> 2) + 4 * half;
        p[rr * 100 + col] = acc[mf][reg];
      }
    }
  }
}

// stage-1 reduction: partial2[by] = sum of 51 partials (15 groups x 51 = 765)
__global__ __launch_bounds__(256) void annred1_kernel(
    const float* __restrict__ partial, float* __restrict__ partial2) {
  const int oi = blockIdx.x * 256 + threadIdx.x;   // < 12800
  const int by = blockIdx.y;                        // 15
  if (oi >= 12800) return;
  const float* p = partial + (size_t)(by * 51) * 12800 + oi;
  float s = 0.0f;
  #pragma unroll 4
  for (int q = 0; q < 51; ++q) s += p[(size_t)q * 12800];
  partial2[(size_t)by * 12800 + oi] = s;
}

// stage-2: sum 15 groups + bias + relu + BN
__global__ __launch_bounds__(256) void annred2_kernel(
    const float* __restrict__ partial2, const float* __restrict__ ab,
    const float* __restrict__ gg, const float* __restrict__ bb,
    const float* __restrict__ mm, const float* __restrict__ vv, float* __restrict__ hid) {
  const int oi = blockIdx.x * 256 + threadIdx.x;   // < 12800
  if (oi < 12800) {
    float s = 0.0f;
    #pragma unroll
    for (int p = 0; p < 15; ++p) s += partial2[(size_t)p * 12800 + oi];
    const int c = oi % 100;
    const float z = fmaxf(s + ab[c], 0.0f);
    hid[oi] = (z - mm[c]) * rsqrtf(vv[c] + 1e-5f) * gg[c] + bb[c];
  }
}

// ---------------- log_prob: MAF collapses to u = a*x + b (mask_out all zeros) ----------------
__global__ __launch_bounds__(256) void logp_kernel(
    const float* __restrict__ x, const float* __restrict__ mob,
    const float* __restrict__ mlg, const float* __restrict__ mbeta, float* __restrict__ lp) {
  const int b = blockIdx.x;
  const int tid = threadIdx.x;
  const float rs = rsqrtf(1.0f + 1e-5f);
  const float A0 = __expf(mlg[0] - mob[1]) * rs;
  const float B0 = -mob[0] * __expf(-mob[1]) * __expf(mlg[0]) * rs + mbeta[0];
  const float A1 = __expf(mlg[1] - mob[3]) * rs;
  const float B1 = -mob[2] * __expf(-mob[3]) * __expf(mlg[1]) * rs + mbeta[1];
  const float S = (mlg[0] - mob[1]) + (mlg[1] - mob[3]) - logf(1.0f + 1e-5f);
  const float a = A1 * A0;
  const float bc = A1 * B0 + B1;
  float s = 0.0f;
  for (int t = tid; t < cKL; t += 256) {
    const float u = a * x[b * cKL + t] + bc;
    s += u * u;
  }
  #pragma unroll
  for (int off = 32; off > 0; off >>= 1) s += __shfl_down(s, off);
  __shared__ float red[4];
  if ((tid & 63) == 0) red[tid >> 6] = s;
  __syncthreads();
  if (tid == 0) {
    const float tot = red[0] + red[1] + red[2] + red[3];
    lp[b] = -0.5f * tot / (float)cKL + (-0.5f * kLOG2PI + S);
  }
}

__global__ void lpmean_kernel(const float* __restrict__ lp, float* __restrict__ outm) {
  __shared__ float red[128];
  const int tid = threadIdx.x;
  red[tid] = lp[tid];
  __syncthreads();
  for (int off = 64; off > 0; off >>= 1) {
    if (tid < off) red[tid] += red[tid + off];
    __syncthreads();
  }
  if (tid == 0) outm[0] = red[0] / 128.0f;
}

extern "C" void kernel_launch(void* const* d_in, const int* in_sizes, int n_in,
                              void* d_out, int out_size, void* d_ws, size_t ws_size,
                              hipStream_t stream) {
  const float* x    = (const float*)d_in[0];
  const float* Wq   = (const float*)d_in[1];
  const float* bq   = (const float*)d_in[2];
  const float* Wk   = (const float*)d_in[3];
  const float* bk   = (const float*)d_in[4];
  const float* Wih  = (const float*)d_in[5];
  const float* Whh  = (const float*)d_in[6];
  const float* bih  = (const float*)d_in[7];
  const float* bhh  = (const float*)d_in[8];
  const float* gWn  = (const float*)d_in[9];
  const float* gbn  = (const float*)d_in[10];
  const float* gWr  = (const float*)d_in[11];
  const float* gW2  = (const float*)d_in[12];
  const float* gb2  = (const float*)d_in[13];
  const float* W1   = (const float*)d_in[14];
  const float* b1   = (const float*)d_in[15];
  const float* bn1g = (const float*)d_in[16];
  const float* bn1b = (const float*)d_in[17];
  const float* bn1m = (const float*)d_in[18];
  const float* bn1v = (const float*)d_in[19];
  const float* W2m  = (const float*)d_in[20];
  const float* b2m  = (const float*)d_in[21];
  const float* bn2g = (const float*)d_in[22];
  const float* bn2b = (const float*)d_in[23];
  const float* bn2m = (const float*)d_in[24];
  const float* bn2v = (const float*)d_in[25];
  const float* W3   = (const float*)d_in[26];
  const float* b3   = (const float*)d_in[27];
  const float* annW = (const float*)d_in[28];
  const float* annb = (const float*)d_in[29];
  const float* abg  = (const float*)d_in[30];
  const float* abb  = (const float*)d_in[31];
  const float* abm  = (const float*)d_in[32];
  const float* abv  = (const float*)d_in[33];
  const float* mob  = (const float*)d_in[38];
  const float* mlg  = (const float*)d_in[39];
  const float* mbeta= (const float*)d_in[40];

  float* ws = (float*)d_ws;
  float* qb    = ws;                    // 391680
  float* kb    = ws + 391680;           // 391680
  float* graph = ws + 783360;           // 332928
  float* hbuf  = ws + 1116288;          // 12533760
  float* z1    = ws + 13650048;         // 64000
  unsigned short* z2bf = (unsigned short*)(ws + 13714048);  // 128x512 bf16
  float* partial  = hbuf;               // ann split-K partials: 765*12800 = 9.79M floats
  float* partial2 = hbuf + 10000000;    // 15*12800 = 192000 floats
  float* mp    = hbuf + 4000000;        // mlp split-K partials (dead before ann)

  float* outF = (float*)d_out;
  float* hid  = outF;                   // 12800
  float* lpm  = outF + 12800;           // 1
  float* hgcn = outF + 12801;           // 12533760
  float* lp   = outF + 12546561;        // 128

  qk_kernel<<<816, 256, 0, stream>>>(x, Wq, bq, Wk, bk, qb, kb);
  attn_kernel<<<128, 256, 0, stream>>>(qb, kb, graph);
  lstm_mfma_kernel<<<408, 64, 0, stream>>>(x, Wih, Whh, bih, bhh, hbuf);
  agg_kernel<<<dim3(15, 128), 256, 0, stream>>>(hbuf, graph, hgcn);
  gnn2_kernel<<<2040, 256, 0, stream>>>(hbuf, gWn, gbn, gWr, gW2, gb2, hgcn);
  gemm_splitk_kernel<<<dim3(8, 48), 256, 0, stream>>>(x, W1, 3060, 500, mp);
  mlpred_kernel<<<250, 256, 0, stream>>>(mp, 48, 500, b1, bn1g, bn1b, bn1m, bn1v, z1);
  gemm_splitk_kernel<<<dim3(8, 8), 256, 0, stream>>>(z1, W2m, 500, 500, mp);
  mlpredbf_kernel<<<256, 256, 0, stream>>>(mp, 8, b2m, bn2g, bn2b, bn2m, bn2v, z2bf);
  w3_mfma_kernel<<<765, 256, 0, stream>>>(z2bf, W3, b3, hgcn);
  ann_mfma_kernel<<<765, 256, 0, stream>>>(hgcn, annW, partial);
  annred1_kernel<<<dim3(50, 15), 256, 0, stream>>>(partial, partial2);
  annred2_kernel<<<50, 256, 0, stream>>>(partial2, annb, abg, abb, abm, abv, hid);
  logp_kernel<<<128, 256, 0, stream>>>(x, mob, mlg, mbeta, lp);
  lpmean_kernel<<<1, 128, 0, stream>>>(lp, lpm);
}